// Round 2
// baseline (499.557 us; speedup 1.0000x reference)
//
#include <hip/hip_runtime.h>
#include <math.h>

#define B_  4
#define L_  8192
#define D_  512
#define BL_ (B_*L_)
#define TOK 64
#define XS  68            // 64 tok + 2 halo + 2 pad
#define KC  16
#define NCH (D_/KC)

// ---------------------------------------------------------------------------
// Signal + e. R1 post-mortem: LDS pipe ~83% busy (weights through LDS).
// New mapping: lane<->token, wave<->32 j-columns. Weights are wave-UNIFORM
// (readfirstlane'd base) -> s_load into SGPRs via scalar cache; x comes from
// LDS as 1 conflict-free b32 per k. LDS traffic drops ~4x; VALU becomes the
// bottleneck (floor ~74us). Staging/conv/e code and all accumulation orders
// for a1/a2/conv are bit-identical to the R1 kernel; only the epilogue
// cross-j reduction order changes (serial 32 + 4-way LDS sum).
// ---------------------------------------------------------------------------
__global__ __launch_bounds__(256, 2) void k_signal(
    const float* __restrict__ x, const float* __restrict__ mask,
    const float* __restrict__ W1, const float* __restrict__ b1,
    const float* __restrict__ W2, const float* __restrict__ b2,
    const float* __restrict__ Wc, const float* __restrict__ bc,
    const float* __restrict__ Wb1, const float* __restrict__ bb1,
    const float* __restrict__ Wb2, const float* __restrict__ bb2,
    float* __restrict__ signal, float* __restrict__ e)
{
  __shared__ float xt[KC][XS];     // x transposed; col 64 = l0-1, 65 = l0+64
  __shared__ float pf[8][XS];      // conv out chunk
  __shared__ float red1[4][TOK];   // epilogue partials
  __shared__ float red2[4][TOK];

  const int t   = threadIdx.x;
  const int blk = blockIdx.x;          // 512 = 4 b x 128 tiles
  const int b   = blk >> 7;
  const int l0  = (blk & 127) << 6;
  const float* xb = x + (size_t)b * L_ * D_;

  const int lane = t & 63;             // token within block
  const int wv   = t >> 6;             // 0..3 -> j-block
  const int wj   = __builtin_amdgcn_readfirstlane(wv << 5);  // uniform

  // x-staging / e role: all 256 threads, one float4 per chunk
  const int stok = t >> 2, skk = t & 3;
  // conv role: out-ch oo_c, adjacent token pair (m2, m2+1)
  const int oo_c = t >> 5;             // 0..7
  const int m2   = (t & 31) << 1;      // 0,2,...,62
  const int cb_c = (oo_c >> 1) << 2;   // rel in-channel base {0,4,8,12}

  float a1[32], a2[32];
#pragma unroll
  for (int j = 0; j < 32; ++j) { a1[j] = 0.f; a2[j] = 0.f; }
  float esacc = 0.f;

  // prefetch registers (next chunk): x + conv weights only
  float4 r_xv, r_hv;
  float4 r_wc0, r_wc1, r_wc2;
  float  r_bc;

  auto LOAD = [&](int c) {
    const int kc = c << 4;
    r_xv = *reinterpret_cast<const float4*>(xb + (size_t)(l0 + stok) * D_ + kc + (skk << 2));
    if (t < 8) {
      const int hh = t >> 2, kk = t & 3;
      const int l = hh ? (l0 + TOK) : (l0 - 1);
      r_hv = make_float4(0.f, 0.f, 0.f, 0.f);
      if (l >= 0 && l < L_)
        r_hv = *reinterpret_cast<const float4*>(xb + (size_t)l * D_ + kc + (kk << 2));
    }
    const int o = (c << 3) + oo_c;
    const float* wcp = Wc + o * 12;
    r_wc0 = *reinterpret_cast<const float4*>(wcp);
    r_wc1 = *reinterpret_cast<const float4*>(wcp + 4);
    r_wc2 = *reinterpret_cast<const float4*>(wcp + 8);
    r_bc  = bc[o];
  };

  LOAD(0);

  for (int c = 0; c < NCH; ++c) {
    const int kc = c << 4;
    __syncthreads();                   // previous chunk fully consumed

    // ---- stage x chunk transposed; accumulate sum(x^2) ----
    {
      const float4 v = r_xv;
      esacc = fmaf(v.x, v.x, esacc); esacc = fmaf(v.y, v.y, esacc);
      esacc = fmaf(v.z, v.z, esacc); esacc = fmaf(v.w, v.w, esacc);
      const int r = skk << 2;
      xt[r + 0][stok] = v.x; xt[r + 1][stok] = v.y;
      xt[r + 2][stok] = v.z; xt[r + 3][stok] = v.w;
    }
    if (t < 8) {
      const int hh = t >> 2, kk = t & 3;
      const int col = TOK + hh, r = kk << 2;
      xt[r + 0][col] = r_hv.x; xt[r + 1][col] = r_hv.y;
      xt[r + 2][col] = r_hv.z; xt[r + 3][col] = r_hv.w;
    }
    __syncthreads();                   // staged data visible

    // keep this chunk's conv weights before the prefetch overwrites them
    float wcl[12];
    wcl[0] = r_wc0.x; wcl[1]  = r_wc0.y; wcl[2]  = r_wc0.z; wcl[3]  = r_wc0.w;
    wcl[4] = r_wc1.x; wcl[5]  = r_wc1.y; wcl[6]  = r_wc1.z; wcl[7]  = r_wc1.w;
    wcl[8] = r_wc2.x; wcl[9]  = r_wc2.y; wcl[10] = r_wc2.z; wcl[11] = r_wc2.w;
    const float bcv = r_bc;

    if (c + 1 < NCH) LOAD(c + 1);      // issue next chunk's global loads

    // ---- conv: out-ch (c*8+oo_c), tokens m2 and m2+1 (unchanged) ----
    {
      float pa = bcv, pb = bcv;
      const int tm1 = (m2 == 0) ? TOK : m2 - 1;
      const int tp2 = (m2 + 2 == TOK) ? TOK + 1 : m2 + 2;
#pragma unroll
      for (int i = 0; i < 4; ++i) {
        const float* row = &xt[cb_c + i][0];
        const float  xm1 = row[tm1];
        const float2 x01 = *reinterpret_cast<const float2*>(&row[m2]);
        const float  xp2 = row[tp2];
        pa = fmaf(xm1,   wcl[i * 3 + 0], pa);
        pa = fmaf(x01.x, wcl[i * 3 + 1], pa);
        pa = fmaf(x01.y, wcl[i * 3 + 2], pa);
        pb = fmaf(x01.x, wcl[i * 3 + 0], pb);
        pb = fmaf(x01.y, wcl[i * 3 + 1], pb);
        pb = fmaf(xp2,   wcl[i * 3 + 2], pb);
      }
      *reinterpret_cast<float2*>(&pf[oo_c][m2]) = make_float2(pa, pb);
    }

    // ---- GEMM x-part: 1 LDS b32 per k + SGPR weights ----
    {
      const float* w1c = W1  + (size_t)kc * 128 + wj;
      const float* wbc = Wb1 + (size_t)kc * 128 + wj;
#pragma unroll
      for (int k = 0; k < KC; ++k) {
        const float xv = xt[k][lane];
        const float* w1r = w1c + (k << 7);
        const float* wbr = wbc + (k << 7);
#pragma unroll
        for (int j = 0; j < 32; ++j) {
          a1[j] = fmaf(xv, w1r[j], a1[j]);
          a2[j] = fmaf(xv, wbr[j], a2[j]);
        }
      }
    }
    __syncthreads();                   // pf writes visible

    // ---- GEMM pf-part ----
    {
      const float* wpc = Wb1 + (size_t)(512 + (c << 3)) * 128 + wj;
#pragma unroll
      for (int oo = 0; oo < 8; ++oo) {
        const float pv = pf[oo][lane];
        const float* wpr = wpc + (oo << 7);
#pragma unroll
        for (int j = 0; j < 32; ++j)
          a2[j] = fmaf(pv, wpr[j], a2[j]);
      }
    }
  }

  // ---- epilogue: relu, project over own 32 j's, cross-wave reduce ----
  {
    float p1 = 0.f, p2 = 0.f;
    const float* b1p  = b1  + wj;
    const float* w2p  = W2  + wj;
    const float* bbp  = bb1 + wj;
    const float* wv2p = Wb2 + wj;
#pragma unroll
    for (int j = 0; j < 32; ++j) {
      const float h1 = a1[j] + b1p[j];
      if (h1 > 0.f) p1 = fmaf(h1, w2p[j], p1);
      const float h2 = a2[j] + bbp[j];
      if (h2 > 0.f) p2 = fmaf(h2, wv2p[j], p2);
    }
    __syncthreads();
    red1[wv][lane] = p1;
    red2[wv][lane] = p2;
    __syncthreads();
    if (wv == 0) {
      const float q1 = ((red1[0][lane] + red1[1][lane]) + red1[2][lane]) + red1[3][lane];
      const float q2 = ((red2[0][lane] + red2[1][lane]) + red2[2][lane]) + red2[3][lane];
      const int gi = b * L_ + l0 + lane;
      const float content = 1.f / (1.f + expf(-(q1 + b2[0])));
      const float bscore  = 1.f / (1.f + expf(-(q2 + bb2[0])));
      signal[gi] = content * (1.f - bscore) * mask[gi];
    }
  }

  // ---- e epilogue: reduce over the 4 skk lanes of each token ----
  {
    float es = esacc;
    es += __shfl_xor(es, 1, 64);
    es += __shfl_xor(es, 2, 64);
    if (skk == 0) {
      const int gi = b * L_ + l0 + stok;
      const float m = mask[gi];
      e[gi] = m * m * es;
    }
  }
}

// ---------------------------------------------------------------------------
// Fused quantile + enforce. One block (1024 thr) per batch row.
// ---------------------------------------------------------------------------
__device__ __forceinline__ int chain_sim(unsigned long long w, int from) {
  int last = -1;
  while (from < 64) {
    const unsigned long long m = w & (~0ull << from);
    if (m == 0ull) break;
    const int p = __ffsll(m) - 1;
    last = p;
    from = p + 4;
  }
  return last;
}

__global__ __launch_bounds__(1024) void k_select(
    const float* __restrict__ signal,
    int* __restrict__ starts, int* __restrict__ nlast, float* __restrict__ bounds)
{
  __shared__ unsigned int bins[4][256];
  __shared__ unsigned int sel_prefix;
  __shared__ int sel_rank;
  __shared__ float sh_thr;
  __shared__ unsigned int wmin[16];
  __shared__ int wcnt[16];
  __shared__ unsigned long long cw[128];
  __shared__ unsigned char nb[L_];
  __shared__ signed char tbl[128][4];
  __shared__ int st_in[128];
  __shared__ int tsum[256];
  __shared__ int offs[257];

  const int b = blockIdx.x, t = threadIdx.x;
  const int wv = t >> 6, lane = t & 63;
  const float* s = signal + b * L_;

  float val[8];
  unsigned int key[8];
#pragma unroll
  for (int i = 0; i < 8; ++i) {
    val[i] = s[(i << 10) + t];
    const unsigned int u = __float_as_uint(val[i]);
    key[i] = (u & 0x80000000u) ? ~u : (u | 0x80000000u);
  }

  // ---- radix select rank 5733 = floor(0.7*(L-1)) ----
  if (t == 0) { sel_prefix = 0u; sel_rank = 5733; }
  __syncthreads();
  for (int round = 0; round < 4; ++round) {
    reinterpret_cast<unsigned int*>(bins)[t] = 0u;
    __syncthreads();
    const unsigned int pre = sel_prefix;
    const int shift = 24 - 8 * round;
#pragma unroll
    for (int i = 0; i < 8; ++i) {
      if (round == 0 || (key[i] >> (shift + 8)) == pre)
        atomicAdd(&bins[t >> 8][(key[i] >> shift) & 255u], 1u);
    }
    __syncthreads();
    if (t < 256)
      bins[0][t] = bins[0][t] + bins[1][t] + bins[2][t] + bins[3][t];
    __syncthreads();
    if (t < 64) {
      const unsigned int c0 = bins[0][(t << 2) + 0], c1 = bins[0][(t << 2) + 1];
      const unsigned int c2 = bins[0][(t << 2) + 2], c3 = bins[0][(t << 2) + 3];
      const unsigned int lsum = c0 + c1 + c2 + c3;
      unsigned int run = lsum;
#pragma unroll
      for (int off = 1; off < 64; off <<= 1) {
        const unsigned int v = __shfl_up(run, off, 64);
        if (t >= off) run += v;
      }
      const int r = sel_rank;
      if (r >= (int)(run - lsum) && r < (int)run) {
        int rr = r - (int)(run - lsum);
        unsigned int cbin;
        if (rr < (int)c0) { cbin = 0; }
        else if (rr < (int)(c0 + c1)) { cbin = 1; rr -= (int)c0; }
        else if (rr < (int)(c0 + c1 + c2)) { cbin = 2; rr -= (int)(c0 + c1); }
        else { cbin = 3; rr -= (int)(c0 + c1 + c2); }
        sel_rank = rr;
        sel_prefix = (pre << 8) | ((unsigned int)(t << 2) | cbin);
      }
    }
    __syncthreads();
  }
  const unsigned int k0 = sel_prefix;

  // ---- successor: count <=k0 and min of keys > k0 (tie-safe) ----
  {
    int cle = 0;
    unsigned int mgt = 0xFFFFFFFFu;
#pragma unroll
    for (int i = 0; i < 8; ++i) {
      if (key[i] <= k0) ++cle;
      else mgt = min(mgt, key[i]);
    }
#pragma unroll
    for (int off = 1; off < 64; off <<= 1) {
      cle += __shfl_xor(cle, off, 64);
      mgt = min(mgt, (unsigned int)__shfl_xor((int)mgt, off, 64));
    }
    if (lane == 0) { wcnt[wv] = cle; wmin[wv] = mgt; }
    __syncthreads();
    if (t == 0) {
      int C = 0; unsigned int M = 0xFFFFFFFFu;
      for (int g = 0; g < 16; ++g) { C += wcnt[g]; M = min(M, wmin[g]); }
      const unsigned int k1 = (C >= 5735) ? k0 : M;
      const unsigned int u0 = (k0 & 0x80000000u) ? (k0 & 0x7fffffffu) : ~k0;
      const unsigned int u1 = (k1 & 0x80000000u) ? (k1 & 0x7fffffffu) : ~k1;
      const float v0 = __uint_as_float(u0);
      const float v1 = __uint_as_float(u1);
      const float g = 0.7f * 8191.0f - 5733.0f;
      sh_thr = v0 + g * (v1 - v0);
    }
    __syncthreads();
  }
  const float thr = sh_thr;

  // ---- candidate bitmap from register values ----
#pragma unroll
  for (int i = 0; i < 8; ++i) {
    const unsigned long long m = __ballot(val[i] < thr);
    if (lane == 0) cw[(i << 4) + wv] = m;
  }
  {
    const int base = t << 3;
#pragma unroll
    for (int i = 0; i < 8; ++i) nb[base + i] = 0;
  }
  __syncthreads();
  if (t == 0) cw[127] |= (1ull << 63);   // forced candidate at L-1
  __syncthreads();

  // ---- (1) per-64-block transition tables ----
  if (t < 512) {
    const int blk = t >> 2, cls = t & 3;
    tbl[blk][cls] = (signed char)chain_sim(cw[blk], cls);
  }
  __syncthreads();

  // ---- (2) serial 128-step state scan ----
  if (t == 0) {
    int st = 0;
    for (int blk = 0; blk < 128; ++blk) {
      const int bs = blk << 6;
      st_in[blk] = st;
      int pl;
      if (blk == 0) {
        pl = chain_sim(cw[0], 4);
      } else {
        int off = st + 4 - bs;
        if (off < 0) off = 0;
        pl = tbl[blk][off];
      }
      if (pl >= 0) st = bs + pl;
    }
  }
  __syncthreads();

  // ---- (3) parallel emission of acceptance + split bytes ----
  if (t < 128) {
    const int bs = t << 6;
    const unsigned long long w = cw[t];
    int st = st_in[t];
    int from = st + 4 - bs;
    if (from < 0) from = 0;
    while (from < 64) {
      const unsigned long long m = w & (~0ull << from);
      if (m == 0ull) break;
      const int p_rel = __ffsll(m) - 1;
      const int p = bs + p_rel;
      nb[p] = 1;
      const int ps = p - st;
      const int k = (ps + 15) >> 4;
      if (k > 1) {
        int sz = ps / k; if (sz < 1) sz = 1;
        for (int j = 1; j < k; ++j) nb[st + j * sz] = 1;
      }
      st = p;
      from = p_rel + 4;
    }
  }
  __syncthreads();

  // ---- prefix scan -> starts / nlast / bounds ----
  if (t < 256) {
    const int base = t << 5;
    int ls = 0;
    for (int i = 0; i < 32; ++i) ls += nb[base + i];
    tsum[t] = ls;
  }
  __syncthreads();
  if (t == 0) {
    int r = 0;
    for (int i = 0; i < 256; ++i) { offs[i] = r; r += tsum[i]; }
    offs[256] = r;
  }
  __syncthreads();
  if (t < 256) {
    const int base = t << 5;
    int run = offs[t];
    for (int i = 0; i < 32; ++i) {
      run += nb[base + i];
      if (nb[base + i]) starts[b * L_ + run] = base + i;
    }
  }
  if (t == 0) { starts[b * L_ + 0] = 0; nlast[b] = offs[256]; }
  __syncthreads();
  const int total = offs[256];
  for (int i = t; i < L_; i += 1024)
    bounds[b * L_ + i] = (i >= 1 && i <= total) ? 1.0f : 0.0f;
}

// ---------------------------------------------------------------------------
// Segment softmax-merge: 4 waves per block (coarsened vs 1-wave blocks to cut
// launch/dispatch overhead); per-wave body and numerics unchanged.
// ---------------------------------------------------------------------------
__global__ __launch_bounds__(256) void k_merge(const float* __restrict__ x,
    const float* __restrict__ mask, const float* __restrict__ e,
    const int* __restrict__ starts, const int* __restrict__ nlast,
    float* __restrict__ merged)
{
  const int idx = (blockIdx.x << 2) + (threadIdx.x >> 6);
  const int b   = idx >> 13;
  const int sid = idx & (L_ - 1);
  const int n = nlast[b];
  const int lane = threadIdx.x & 63;
  const int c0 = lane << 3;
  float* o = merged + (size_t)(b * L_ + sid) * D_ + c0;
  if (sid > n) {
    const float4 z = make_float4(0.f, 0.f, 0.f, 0.f);
    reinterpret_cast<float4*>(o)[0] = z;
    reinterpret_cast<float4*>(o)[1] = z;
    return;
  }
  const int t0 = starts[b * L_ + sid];
  const int t1 = (sid < n) ? starts[b * L_ + sid + 1] : L_;
  const float* eb = e + b * L_;

  float mx = -INFINITY;
  for (int p = t0; p < t1; ++p) mx = fmaxf(mx, eb[p]);
  float den = 0.f;
  for (int p = t0; p < t1; ++p) den += expf(eb[p] - mx);

  float acc[8] = {0,0,0,0,0,0,0,0};
  for (int p = t0; p < t1; ++p) {
    const float wn = expf(eb[p] - mx) / den;
    const float sc = wn * mask[b * L_ + p];
    const float* xr = x + ((size_t)(b * L_ + p)) * D_ + c0;
    const float4 u0 = reinterpret_cast<const float4*>(xr)[0];
    const float4 u1 = reinterpret_cast<const float4*>(xr)[1];
    acc[0] = fmaf(sc, u0.x, acc[0]); acc[1] = fmaf(sc, u0.y, acc[1]);
    acc[2] = fmaf(sc, u0.z, acc[2]); acc[3] = fmaf(sc, u0.w, acc[3]);
    acc[4] = fmaf(sc, u1.x, acc[4]); acc[5] = fmaf(sc, u1.y, acc[5]);
    acc[6] = fmaf(sc, u1.z, acc[6]); acc[7] = fmaf(sc, u1.w, acc[7]);
  }
  reinterpret_cast<float4*>(o)[0] = make_float4(acc[0], acc[1], acc[2], acc[3]);
  reinterpret_cast<float4*>(o)[1] = make_float4(acc[4], acc[5], acc[6], acc[7]);
}

// ---------------------------------------------------------------------------
extern "C" void kernel_launch(void* const* d_in, const int* in_sizes, int n_in,
                              void* d_out, int out_size, void* d_ws, size_t ws_size,
                              hipStream_t stream) {
  (void)in_sizes; (void)n_in; (void)out_size; (void)ws_size;
  const float* x    = (const float*)d_in[0];
  const float* mask = (const float*)d_in[1];
  const float* W1   = (const float*)d_in[2];
  const float* b1   = (const float*)d_in[3];
  const float* W2   = (const float*)d_in[4];
  const float* b2   = (const float*)d_in[5];
  const float* Wc   = (const float*)d_in[6];
  const float* bc   = (const float*)d_in[7];
  const float* Wb1  = (const float*)d_in[8];
  const float* bb1  = (const float*)d_in[9];
  const float* Wb2  = (const float*)d_in[10];
  const float* bb2  = (const float*)d_in[11];

  float* merged = (float*)d_out;
  float* bounds = (float*)d_out + (size_t)BL_ * D_;

  char* ws = (char*)d_ws;
  float* signal = (float*)(ws);
  float* e      = (float*)(ws + (size_t)BL_ * 4);
  int*   starts = (int*)  (ws + (size_t)BL_ * 8);
  int*   nlast  = (int*)  (ws + (size_t)BL_ * 12);

  k_signal<<<BL_ / TOK, 256, 0, stream>>>(x, mask, W1, b1, W2, b2, Wc, bc,
                                          Wb1, bb1, Wb2, bb2, signal, e);
  k_select<<<B_, 1024, 0, stream>>>(signal, starts, nlast, bounds);
  k_merge<<<BL_ / 4, 256, 0, stream>>>(x, mask, e, starts, nlast, merged);
}

// Round 3
// 379.174 us; speedup vs baseline: 1.3175x; 1.3175x over previous
//
#include <hip/hip_runtime.h>
#include <math.h>

#define B_  4
#define L_  8192
#define D_  512
#define BL_ (B_*L_)
#define TOK 64
#define XS  68            // 64 tok + 2 halo + 2 pad
#define KC  16
#define NCH (D_/KC)

// ---------------------------------------------------------------------------
// Signal + e. R2 post-mortem: scalar-cache weight path serialized (VALUBusy
// 20%). R3: weights back in LDS, but wave shaped 8 tok-rows x 8 j-cols with
// per-thread tile 8x8: per k only 6 ds_read_b128 (8-addr broadcast, 2-way
// banked = free) feed 128 wave-FMAs -> VALU-bound with LDS at ~55%.
// 128 threads/block (2 waves), 64 tok x 128 j per block, grid 512 (2/CU:
// sibling block hides staging stalls). Weight staging flat-linear b128
// (conflict-free). a1/a2/conv/pf contraction orders identical to R1.
// ---------------------------------------------------------------------------
__global__ __launch_bounds__(128, 1) void k_signal(
    const float* __restrict__ x, const float* __restrict__ mask,
    const float* __restrict__ W1, const float* __restrict__ b1,
    const float* __restrict__ W2, const float* __restrict__ b2,
    const float* __restrict__ Wc, const float* __restrict__ bc,
    const float* __restrict__ Wb1, const float* __restrict__ bb1,
    const float* __restrict__ Wb2, const float* __restrict__ bb2,
    float* __restrict__ signal, float* __restrict__ e)
{
  __shared__ float ws1[KC][128];   // W1 chunk rows kc..kc+15
  __shared__ float wsb[KC][128];   // Wb1 x-part chunk
  __shared__ float wsp[8][128];    // Wb1 pf-part chunk
  __shared__ float xt[KC][XS];     // x transposed; col 64 = l0-1, 65 = l0+64
  __shared__ float pf[8][XS];      // conv out chunk
  __shared__ float red1[2][TOK];   // epilogue cross-wave partials
  __shared__ float red2[2][TOK];

  const int t   = threadIdx.x;
  const int blk = blockIdx.x;          // 512 = 4 b x 128 tiles
  const int b   = blk >> 7;
  const int l0  = (blk & 127) << 6;
  const float* xb = x + (size_t)b * L_ * D_;

  // GEMM mapping: wave = 8 tok-rows x 8 j-cols; thread = 8 tok x 8 j
  const int lane = t & 63, wv = t >> 6;
  const int r8 = lane >> 3, c8 = lane & 7;
  const int tok0 = r8 << 3;
  const int j0   = (((wv << 3) + c8) << 3);   // 16 cols x 8 j = 128 j

  // staging role: token = t>>1, k-half = (t&1)*8  (2 float4 per thread)
  const int stok = t >> 1, khalf = (t & 1) << 3;
  // conv role: out-ch oo_c (0..7), 4 tokens starting at tokq (2 pairs)
  const int oo_c = t >> 4;
  const int tokq = (t & 15) << 2;
  const int cb_c = (oo_c >> 1) << 2;   // rel in-channel base {0,4,8,12}

  float a1[8][8], a2[8][8];
#pragma unroll
  for (int i = 0; i < 8; ++i)
#pragma unroll
    for (int j = 0; j < 8; ++j) { a1[i][j] = 0.f; a2[i][j] = 0.f; }
  float esacc = 0.f;

  // prefetch registers (next chunk): x + halo + conv weights
  float4 r_xv0, r_xv1, r_hv;
  float4 r_wc0, r_wc1, r_wc2;
  float  r_bc;

  auto LOAD = [&](int c) {
    const int kc = c << 4;
    const float* xr = xb + (size_t)(l0 + stok) * D_ + kc + khalf;
    r_xv0 = *reinterpret_cast<const float4*>(xr);
    r_xv1 = *reinterpret_cast<const float4*>(xr + 4);
    if (t < 8) {
      const int hh = t >> 2, kk = t & 3;
      const int l = hh ? (l0 + TOK) : (l0 - 1);
      r_hv = make_float4(0.f, 0.f, 0.f, 0.f);
      if (l >= 0 && l < L_)
        r_hv = *reinterpret_cast<const float4*>(xb + (size_t)l * D_ + kc + (kk << 2));
    }
    const int o = (c << 3) + oo_c;
    const float* wcp = Wc + o * 12;
    r_wc0 = *reinterpret_cast<const float4*>(wcp);
    r_wc1 = *reinterpret_cast<const float4*>(wcp + 4);
    r_wc2 = *reinterpret_cast<const float4*>(wcp + 8);
    r_bc  = bc[o];
  };

  LOAD(0);

  for (int c = 0; c < NCH; ++c) {
    const int kc = c << 4;
    __syncthreads();                   // previous chunk fully consumed

    // ---- stage weights flat-linear (conflict-free b128 writes) ----
    {
      const float* w1g = W1  + (size_t)kc * 128;
      const float* wbg = Wb1 + (size_t)kc * 128;
      const float* wpg = Wb1 + (size_t)(512 + (c << 3)) * 128;
      float* ws1f = &ws1[0][0];
      float* wsbf = &wsb[0][0];
      float* wspf = &wsp[0][0];
#pragma unroll
      for (int q = 0; q < 4; ++q) {
        const int fi = (t + (q << 7)) << 2;
        *reinterpret_cast<float4*>(ws1f + fi) =
            *reinterpret_cast<const float4*>(w1g + fi);
        *reinterpret_cast<float4*>(wsbf + fi) =
            *reinterpret_cast<const float4*>(wbg + fi);
      }
#pragma unroll
      for (int q = 0; q < 2; ++q) {
        const int fi = (t + (q << 7)) << 2;
        *reinterpret_cast<float4*>(wspf + fi) =
            *reinterpret_cast<const float4*>(wpg + fi);
      }
    }

    // ---- stage x chunk transposed; accumulate sum(x^2) ----
    {
      float4 v = r_xv0;
      esacc = fmaf(v.x, v.x, esacc); esacc = fmaf(v.y, v.y, esacc);
      esacc = fmaf(v.z, v.z, esacc); esacc = fmaf(v.w, v.w, esacc);
      xt[khalf + 0][stok] = v.x; xt[khalf + 1][stok] = v.y;
      xt[khalf + 2][stok] = v.z; xt[khalf + 3][stok] = v.w;
      v = r_xv1;
      esacc = fmaf(v.x, v.x, esacc); esacc = fmaf(v.y, v.y, esacc);
      esacc = fmaf(v.z, v.z, esacc); esacc = fmaf(v.w, v.w, esacc);
      xt[khalf + 4][stok] = v.x; xt[khalf + 5][stok] = v.y;
      xt[khalf + 6][stok] = v.z; xt[khalf + 7][stok] = v.w;
    }
    if (t < 8) {
      const int hh = t >> 2, kk = t & 3;
      const int col = TOK + hh, r = kk << 2;
      xt[r + 0][col] = r_hv.x; xt[r + 1][col] = r_hv.y;
      xt[r + 2][col] = r_hv.z; xt[r + 3][col] = r_hv.w;
    }
    __syncthreads();                   // staged data visible

    // keep this chunk's conv weights before the prefetch overwrites them
    float wcl[12];
    wcl[0] = r_wc0.x; wcl[1]  = r_wc0.y; wcl[2]  = r_wc0.z; wcl[3]  = r_wc0.w;
    wcl[4] = r_wc1.x; wcl[5]  = r_wc1.y; wcl[6]  = r_wc1.z; wcl[7]  = r_wc1.w;
    wcl[8] = r_wc2.x; wcl[9]  = r_wc2.y; wcl[10] = r_wc2.z; wcl[11] = r_wc2.w;
    const float bcv = r_bc;

    if (c + 1 < NCH) LOAD(c + 1);      // issue next chunk's global loads

    // ---- conv: out-ch (c*8+oo_c), 2 adjacent-token pairs ----
#pragma unroll
    for (int pp = 0; pp < 2; ++pp) {
      const int m2 = tokq + (pp << 1);
      float pa = bcv, pb = bcv;
      const int tm1 = (m2 == 0) ? TOK : m2 - 1;
      const int tp2 = (m2 + 2 == TOK) ? TOK + 1 : m2 + 2;
#pragma unroll
      for (int i = 0; i < 4; ++i) {
        const float* row = &xt[cb_c + i][0];
        const float  xm1 = row[tm1];
        const float2 x01 = *reinterpret_cast<const float2*>(&row[m2]);
        const float  xp2 = row[tp2];
        pa = fmaf(xm1,   wcl[i * 3 + 0], pa);
        pa = fmaf(x01.x, wcl[i * 3 + 1], pa);
        pa = fmaf(x01.y, wcl[i * 3 + 2], pa);
        pb = fmaf(x01.x, wcl[i * 3 + 0], pb);
        pb = fmaf(x01.y, wcl[i * 3 + 1], pb);
        pb = fmaf(xp2,   wcl[i * 3 + 2], pb);
      }
      *reinterpret_cast<float2*>(&pf[oo_c][m2]) = make_float2(pa, pb);
    }

    // ---- x-GEMM: 6 b128 (broadcast) -> 128 FMA per k ----
#pragma unroll 4
    for (int k = 0; k < KC; ++k) {
      const float4 xa  = *reinterpret_cast<const float4*>(&xt[k][tok0]);
      const float4 xc  = *reinterpret_cast<const float4*>(&xt[k][tok0 + 4]);
      const float4 w1a = *reinterpret_cast<const float4*>(&ws1[k][j0]);
      const float4 w1b = *reinterpret_cast<const float4*>(&ws1[k][j0 + 4]);
      const float4 wba = *reinterpret_cast<const float4*>(&wsb[k][j0]);
      const float4 wbb = *reinterpret_cast<const float4*>(&wsb[k][j0 + 4]);
      const float xs8[8] = {xa.x, xa.y, xa.z, xa.w, xc.x, xc.y, xc.z, xc.w};
#pragma unroll
      for (int i = 0; i < 8; ++i) {
        const float xs = xs8[i];
        a1[i][0] = fmaf(xs, w1a.x, a1[i][0]);
        a1[i][1] = fmaf(xs, w1a.y, a1[i][1]);
        a1[i][2] = fmaf(xs, w1a.z, a1[i][2]);
        a1[i][3] = fmaf(xs, w1a.w, a1[i][3]);
        a1[i][4] = fmaf(xs, w1b.x, a1[i][4]);
        a1[i][5] = fmaf(xs, w1b.y, a1[i][5]);
        a1[i][6] = fmaf(xs, w1b.z, a1[i][6]);
        a1[i][7] = fmaf(xs, w1b.w, a1[i][7]);
        a2[i][0] = fmaf(xs, wba.x, a2[i][0]);
        a2[i][1] = fmaf(xs, wba.y, a2[i][1]);
        a2[i][2] = fmaf(xs, wba.z, a2[i][2]);
        a2[i][3] = fmaf(xs, wba.w, a2[i][3]);
        a2[i][4] = fmaf(xs, wbb.x, a2[i][4]);
        a2[i][5] = fmaf(xs, wbb.y, a2[i][5]);
        a2[i][6] = fmaf(xs, wbb.z, a2[i][6]);
        a2[i][7] = fmaf(xs, wbb.w, a2[i][7]);
      }
    }
    __syncthreads();                   // pf writes visible

    // ---- pf-GEMM ----
#pragma unroll 2
    for (int oo = 0; oo < 8; ++oo) {
      const float4 pa4 = *reinterpret_cast<const float4*>(&pf[oo][tok0]);
      const float4 pb4 = *reinterpret_cast<const float4*>(&pf[oo][tok0 + 4]);
      const float4 wpa = *reinterpret_cast<const float4*>(&wsp[oo][j0]);
      const float4 wpb = *reinterpret_cast<const float4*>(&wsp[oo][j0 + 4]);
      const float ps8[8] = {pa4.x, pa4.y, pa4.z, pa4.w,
                            pb4.x, pb4.y, pb4.z, pb4.w};
#pragma unroll
      for (int i = 0; i < 8; ++i) {
        const float ps = ps8[i];
        a2[i][0] = fmaf(ps, wpa.x, a2[i][0]);
        a2[i][1] = fmaf(ps, wpa.y, a2[i][1]);
        a2[i][2] = fmaf(ps, wpa.z, a2[i][2]);
        a2[i][3] = fmaf(ps, wpa.w, a2[i][3]);
        a2[i][4] = fmaf(ps, wpb.x, a2[i][4]);
        a2[i][5] = fmaf(ps, wpb.y, a2[i][5]);
        a2[i][6] = fmaf(ps, wpb.z, a2[i][6]);
        a2[i][7] = fmaf(ps, wpb.w, a2[i][7]);
      }
    }
  }

  // ---- epilogue: relu, project own 8 j, shfl over 8 cols, LDS over waves ----
  {
    const float bias2 = b2[0], biasb2 = bb2[0];
    float p1[8], p2[8];
#pragma unroll
    for (int i = 0; i < 8; ++i) {
      float s1 = 0.f, s2 = 0.f;
#pragma unroll
      for (int jj = 0; jj < 8; ++jj) {
        const float h1 = a1[i][jj] + b1[j0 + jj];
        if (h1 > 0.f) s1 = fmaf(h1, W2[j0 + jj], s1);
        const float h2 = a2[i][jj] + bb1[j0 + jj];
        if (h2 > 0.f) s2 = fmaf(h2, Wb2[j0 + jj], s2);
      }
#pragma unroll
      for (int off = 1; off < 8; off <<= 1) {
        s1 += __shfl_xor(s1, off, 64);
        s2 += __shfl_xor(s2, off, 64);
      }
      p1[i] = s1; p2[i] = s2;
    }
    __syncthreads();
    if (c8 == 0) {
#pragma unroll
      for (int i = 0; i < 8; ++i) {
        red1[wv][tok0 + i] = p1[i];
        red2[wv][tok0 + i] = p2[i];
      }
    }
    __syncthreads();
    if (t < TOK) {
      const float q1 = red1[0][t] + red1[1][t];
      const float q2 = red2[0][t] + red2[1][t];
      const int gi = b * L_ + l0 + t;
      const float content = 1.f / (1.f + expf(-(q1 + bias2)));
      const float bscore  = 1.f / (1.f + expf(-(q2 + biasb2)));
      signal[gi] = content * (1.f - bscore) * mask[gi];
    }
  }

  // ---- e epilogue: reduce over the 2 k-half lanes of each token ----
  {
    float es = esacc;
    es += __shfl_xor(es, 1, 64);
    if ((t & 1) == 0) {
      const int gi = b * L_ + l0 + stok;
      const float m = mask[gi];
      e[gi] = m * m * es;
    }
  }
}

// ---------------------------------------------------------------------------
// Fused quantile + enforce. One block (1024 thr) per batch row.
// ---------------------------------------------------------------------------
__device__ __forceinline__ int chain_sim(unsigned long long w, int from) {
  int last = -1;
  while (from < 64) {
    const unsigned long long m = w & (~0ull << from);
    if (m == 0ull) break;
    const int p = __ffsll(m) - 1;
    last = p;
    from = p + 4;
  }
  return last;
}

__global__ __launch_bounds__(1024) void k_select(
    const float* __restrict__ signal,
    int* __restrict__ starts, int* __restrict__ nlast, float* __restrict__ bounds)
{
  __shared__ unsigned int bins[4][256];
  __shared__ unsigned int sel_prefix;
  __shared__ int sel_rank;
  __shared__ float sh_thr;
  __shared__ unsigned int wmin[16];
  __shared__ int wcnt[16];
  __shared__ unsigned long long cw[128];
  __shared__ unsigned char nb[L_];
  __shared__ signed char tbl[128][4];
  __shared__ int st_in[128];
  __shared__ int tsum[256];
  __shared__ int offs[257];

  const int b = blockIdx.x, t = threadIdx.x;
  const int wv = t >> 6, lane = t & 63;
  const float* s = signal + b * L_;

  float val[8];
  unsigned int key[8];
#pragma unroll
  for (int i = 0; i < 8; ++i) {
    val[i] = s[(i << 10) + t];
    const unsigned int u = __float_as_uint(val[i]);
    key[i] = (u & 0x80000000u) ? ~u : (u | 0x80000000u);
  }

  // ---- radix select rank 5733 = floor(0.7*(L-1)) ----
  if (t == 0) { sel_prefix = 0u; sel_rank = 5733; }
  __syncthreads();
  for (int round = 0; round < 4; ++round) {
    reinterpret_cast<unsigned int*>(bins)[t] = 0u;
    __syncthreads();
    const unsigned int pre = sel_prefix;
    const int shift = 24 - 8 * round;
#pragma unroll
    for (int i = 0; i < 8; ++i) {
      if (round == 0 || (key[i] >> (shift + 8)) == pre)
        atomicAdd(&bins[t >> 8][(key[i] >> shift) & 255u], 1u);
    }
    __syncthreads();
    if (t < 256)
      bins[0][t] = bins[0][t] + bins[1][t] + bins[2][t] + bins[3][t];
    __syncthreads();
    if (t < 64) {
      const unsigned int c0 = bins[0][(t << 2) + 0], c1 = bins[0][(t << 2) + 1];
      const unsigned int c2 = bins[0][(t << 2) + 2], c3 = bins[0][(t << 2) + 3];
      const unsigned int lsum = c0 + c1 + c2 + c3;
      unsigned int run = lsum;
#pragma unroll
      for (int off = 1; off < 64; off <<= 1) {
        const unsigned int v = __shfl_up(run, off, 64);
        if (t >= off) run += v;
      }
      const int r = sel_rank;
      if (r >= (int)(run - lsum) && r < (int)run) {
        int rr = r - (int)(run - lsum);
        unsigned int cbin;
        if (rr < (int)c0) { cbin = 0; }
        else if (rr < (int)(c0 + c1)) { cbin = 1; rr -= (int)c0; }
        else if (rr < (int)(c0 + c1 + c2)) { cbin = 2; rr -= (int)(c0 + c1); }
        else { cbin = 3; rr -= (int)(c0 + c1 + c2); }
        sel_rank = rr;
        sel_prefix = (pre << 8) | ((unsigned int)(t << 2) | cbin);
      }
    }
    __syncthreads();
  }
  const unsigned int k0 = sel_prefix;

  // ---- successor: count <=k0 and min of keys > k0 (tie-safe) ----
  {
    int cle = 0;
    unsigned int mgt = 0xFFFFFFFFu;
#pragma unroll
    for (int i = 0; i < 8; ++i) {
      if (key[i] <= k0) ++cle;
      else mgt = min(mgt, key[i]);
    }
#pragma unroll
    for (int off = 1; off < 64; off <<= 1) {
      cle += __shfl_xor(cle, off, 64);
      mgt = min(mgt, (unsigned int)__shfl_xor((int)mgt, off, 64));
    }
    if (lane == 0) { wcnt[wv] = cle; wmin[wv] = mgt; }
    __syncthreads();
    if (t == 0) {
      int C = 0; unsigned int M = 0xFFFFFFFFu;
      for (int g = 0; g < 16; ++g) { C += wcnt[g]; M = min(M, wmin[g]); }
      const unsigned int k1 = (C >= 5735) ? k0 : M;
      const unsigned int u0 = (k0 & 0x80000000u) ? (k0 & 0x7fffffffu) : ~k0;
      const unsigned int u1 = (k1 & 0x80000000u) ? (k1 & 0x7fffffffu) : ~k1;
      const float v0 = __uint_as_float(u0);
      const float v1 = __uint_as_float(u1);
      const float g = 0.7f * 8191.0f - 5733.0f;
      sh_thr = v0 + g * (v1 - v0);
    }
    __syncthreads();
  }
  const float thr = sh_thr;

  // ---- candidate bitmap from register values ----
#pragma unroll
  for (int i = 0; i < 8; ++i) {
    const unsigned long long m = __ballot(val[i] < thr);
    if (lane == 0) cw[(i << 4) + wv] = m;
  }
  {
    const int base = t << 3;
#pragma unroll
    for (int i = 0; i < 8; ++i) nb[base + i] = 0;
  }
  __syncthreads();
  if (t == 0) cw[127] |= (1ull << 63);   // forced candidate at L-1
  __syncthreads();

  // ---- (1) per-64-block transition tables ----
  if (t < 512) {
    const int blk = t >> 2, cls = t & 3;
    tbl[blk][cls] = (signed char)chain_sim(cw[blk], cls);
  }
  __syncthreads();

  // ---- (2) serial 128-step state scan ----
  if (t == 0) {
    int st = 0;
    for (int blk = 0; blk < 128; ++blk) {
      const int bs = blk << 6;
      st_in[blk] = st;
      int pl;
      if (blk == 0) {
        pl = chain_sim(cw[0], 4);
      } else {
        int off = st + 4 - bs;
        if (off < 0) off = 0;
        pl = tbl[blk][off];
      }
      if (pl >= 0) st = bs + pl;
    }
  }
  __syncthreads();

  // ---- (3) parallel emission of acceptance + split bytes ----
  if (t < 128) {
    const int bs = t << 6;
    const unsigned long long w = cw[t];
    int st = st_in[t];
    int from = st + 4 - bs;
    if (from < 0) from = 0;
    while (from < 64) {
      const unsigned long long m = w & (~0ull << from);
      if (m == 0ull) break;
      const int p_rel = __ffsll(m) - 1;
      const int p = bs + p_rel;
      nb[p] = 1;
      const int ps = p - st;
      const int k = (ps + 15) >> 4;
      if (k > 1) {
        int sz = ps / k; if (sz < 1) sz = 1;
        for (int j = 1; j < k; ++j) nb[st + j * sz] = 1;
      }
      st = p;
      from = p_rel + 4;
    }
  }
  __syncthreads();

  // ---- prefix scan -> starts / nlast / bounds ----
  if (t < 256) {
    const int base = t << 5;
    int ls = 0;
    for (int i = 0; i < 32; ++i) ls += nb[base + i];
    tsum[t] = ls;
  }
  __syncthreads();
  if (t == 0) {
    int r = 0;
    for (int i = 0; i < 256; ++i) { offs[i] = r; r += tsum[i]; }
    offs[256] = r;
  }
  __syncthreads();
  if (t < 256) {
    const int base = t << 5;
    int run = offs[t];
    for (int i = 0; i < 32; ++i) {
      run += nb[base + i];
      if (nb[base + i]) starts[b * L_ + run] = base + i;
    }
  }
  if (t == 0) { starts[b * L_ + 0] = 0; nlast[b] = offs[256]; }
  __syncthreads();
  const int total = offs[256];
  for (int i = t; i < L_; i += 1024)
    bounds[b * L_ + i] = (i >= 1 && i <= total) ? 1.0f : 0.0f;
}

// ---------------------------------------------------------------------------
// Segment softmax-merge: 4 waves per block; per-wave body unchanged.
// ---------------------------------------------------------------------------
__global__ __launch_bounds__(256) void k_merge(const float* __restrict__ x,
    const float* __restrict__ mask, const float* __restrict__ e,
    const int* __restrict__ starts, const int* __restrict__ nlast,
    float* __restrict__ merged)
{
  const int idx = (blockIdx.x << 2) + (threadIdx.x >> 6);
  const int b   = idx >> 13;
  const int sid = idx & (L_ - 1);
  const int n = nlast[b];
  const int lane = threadIdx.x & 63;
  const int c0 = lane << 3;
  float* o = merged + (size_t)(b * L_ + sid) * D_ + c0;
  if (sid > n) {
    const float4 z = make_float4(0.f, 0.f, 0.f, 0.f);
    reinterpret_cast<float4*>(o)[0] = z;
    reinterpret_cast<float4*>(o)[1] = z;
    return;
  }
  const int t0 = starts[b * L_ + sid];
  const int t1 = (sid < n) ? starts[b * L_ + sid + 1] : L_;
  const float* eb = e + b * L_;

  float mx = -INFINITY;
  for (int p = t0; p < t1; ++p) mx = fmaxf(mx, eb[p]);
  float den = 0.f;
  for (int p = t0; p < t1; ++p) den += expf(eb[p] - mx);

  float acc[8] = {0,0,0,0,0,0,0,0};
  for (int p = t0; p < t1; ++p) {
    const float wn = expf(eb[p] - mx) / den;
    const float sc = wn * mask[b * L_ + p];
    const float* xr = x + ((size_t)(b * L_ + p)) * D_ + c0;
    const float4 u0 = reinterpret_cast<const float4*>(xr)[0];
    const float4 u1 = reinterpret_cast<const float4*>(xr)[1];
    acc[0] = fmaf(sc, u0.x, acc[0]); acc[1] = fmaf(sc, u0.y, acc[1]);
    acc[2] = fmaf(sc, u0.z, acc[2]); acc[3] = fmaf(sc, u0.w, acc[3]);
    acc[4] = fmaf(sc, u1.x, acc[4]); acc[5] = fmaf(sc, u1.y, acc[5]);
    acc[6] = fmaf(sc, u1.z, acc[6]); acc[7] = fmaf(sc, u1.w, acc[7]);
  }
  reinterpret_cast<float4*>(o)[0] = make_float4(acc[0], acc[1], acc[2], acc[3]);
  reinterpret_cast<float4*>(o)[1] = make_float4(acc[4], acc[5], acc[6], acc[7]);
}

// ---------------------------------------------------------------------------
extern "C" void kernel_launch(void* const* d_in, const int* in_sizes, int n_in,
                              void* d_out, int out_size, void* d_ws, size_t ws_size,
                              hipStream_t stream) {
  (void)in_sizes; (void)n_in; (void)out_size; (void)ws_size;
  const float* x    = (const float*)d_in[0];
  const float* mask = (const float*)d_in[1];
  const float* W1   = (const float*)d_in[2];
  const float* b1   = (const float*)d_in[3];
  const float* W2   = (const float*)d_in[4];
  const float* b2   = (const float*)d_in[5];
  const float* Wc   = (const float*)d_in[6];
  const float* bc   = (const float*)d_in[7];
  const float* Wb1  = (const float*)d_in[8];
  const float* bb1  = (const float*)d_in[9];
  const float* Wb2  = (const float*)d_in[10];
  const float* bb2  = (const float*)d_in[11];

  float* merged = (float*)d_out;
  float* bounds = (float*)d_out + (size_t)BL_ * D_;

  char* ws = (char*)d_ws;
  float* signal = (float*)(ws);
  float* e      = (float*)(ws + (size_t)BL_ * 4);
  int*   starts = (int*)  (ws + (size_t)BL_ * 8);
  int*   nlast  = (int*)  (ws + (size_t)BL_ * 12);

  k_signal<<<BL_ / TOK, 128, 0, stream>>>(x, mask, W1, b1, W2, b2, Wc, bc,
                                          Wb1, bb1, Wb2, bb2, signal, e);
  k_select<<<B_, 1024, 0, stream>>>(signal, starts, nlast, bounds);
  k_merge<<<BL_ / 4, 256, 0, stream>>>(x, mask, e, starts, nlast, merged);
}

// Round 4
// 328.481 us; speedup vs baseline: 1.5208x; 1.1543x over previous
//
#include <hip/hip_runtime.h>
#include <math.h>

#define B_  4
#define L_  8192
#define D_  512
#define BL_ (B_*L_)
#define TOK 64
#define XS  68            // 64 tok + 2 halo + 2 pad (272B rows, 16B aligned)
#define WS_ 132           // weight row pad: +4 floats (528B rows, 16B aligned)
#define KC  16
#define NCH (D_/KC)

// ---------------------------------------------------------------------------
// Signal + e. R3 post-mortem: 8x8 tiles need >=2 waves/SIMD. R4: in-wave
// k-split — lane = (kh, r8, c8); kh = k-parity (krow = 2*kk+kh). Thread tile
// 8 tok x 8 j (6 b128 / 128 FMA per kk), wave = 32 tok x 64 j x 2 k-parities,
// block = 256 thr = 64 tok x 128 j -> grid 512, 2 blocks/CU, 8 waves/CU.
// k-parity partials merge via one shfl_xor(32) per acc at the end.
// Bank layout: WS_=132 pad + kh-interleaved krow -> x reads conflict-free,
// weight reads 2-way (free). pf-GEMM split by oo-parity identically.
// Staging/conv/e identical to R1's 256-thread pattern.
// ---------------------------------------------------------------------------
__global__ __launch_bounds__(256, 2) void k_signal(
    const float* __restrict__ x, const float* __restrict__ mask,
    const float* __restrict__ W1, const float* __restrict__ b1,
    const float* __restrict__ W2, const float* __restrict__ b2,
    const float* __restrict__ Wc, const float* __restrict__ bc,
    const float* __restrict__ Wb1, const float* __restrict__ bb1,
    const float* __restrict__ Wb2, const float* __restrict__ bb2,
    float* __restrict__ signal, float* __restrict__ e)
{
  __shared__ float ws1[KC][WS_];   // W1 chunk rows kc..kc+15
  __shared__ float wsb[KC][WS_];   // Wb1 x-part chunk
  __shared__ float wsp[8][WS_];    // Wb1 pf-part chunk
  __shared__ float xt[KC][XS];     // x transposed; col 64 = l0-1, 65 = l0+64
  __shared__ float pf[8][XS];      // conv out chunk
  __shared__ float red1[2][TOK];   // epilogue cross-jh partials
  __shared__ float red2[2][TOK];

  const int t   = threadIdx.x;
  const int blk = blockIdx.x;          // 512 = 4 b x 128 tiles
  const int b   = blk >> 7;
  const int l0  = (blk & 127) << 6;
  const float* xb = x + (size_t)b * L_ * D_;

  // GEMM mapping: lane = (kh, r8, c8); wave wv = (th, jh)
  const int lane = t & 63, wv = t >> 6;
  const int c8 = lane & 7, r8 = (lane >> 3) & 3, kh = lane >> 5;
  const int jh = wv & 1, th = wv >> 1;
  const int j0   = (jh << 6) + (c8 << 3);   // [0,128)
  const int tok0 = (th << 5) + (r8 << 3);   // [0,64)

  // staging role: token = t>>2, k-quad = t&3 (1 float4 per thread)
  const int stok = t >> 2, skk = t & 3;
  // conv role: out-ch oo_c (0..7), adjacent token pair (m2, m2+1)
  const int oo_c = t >> 5;
  const int m2   = (t & 31) << 1;
  const int cb_c = (oo_c >> 1) << 2;

  float a1[8][8], a2[8][8];
#pragma unroll
  for (int i = 0; i < 8; ++i)
#pragma unroll
    for (int j = 0; j < 8; ++j) { a1[i][j] = 0.f; a2[i][j] = 0.f; }
  float esacc = 0.f;

  // prefetch registers (next chunk)
  float4 r_xv, r_hv;
  float4 r_w1q0, r_w1q1, r_wbq0, r_wbq1, r_wpq;
  float4 r_wc0, r_wc1, r_wc2;
  float  r_bc;

  auto LOAD = [&](int c) {
    const int kc = c << 4;
    r_xv = *reinterpret_cast<const float4*>(
        xb + (size_t)(l0 + stok) * D_ + kc + (skk << 2));
    if (t < 8) {
      const int hh = t >> 2, kk = t & 3;
      const int l = hh ? (l0 + TOK) : (l0 - 1);
      r_hv = make_float4(0.f, 0.f, 0.f, 0.f);
      if (l >= 0 && l < L_)
        r_hv = *reinterpret_cast<const float4*>(xb + (size_t)l * D_ + kc + (kk << 2));
    }
    {
      const float* w1g = W1  + (size_t)kc * 128;
      const float* wbg = Wb1 + (size_t)kc * 128;
      const float* wpg = Wb1 + (size_t)(512 + (c << 3)) * 128;
      r_w1q0 = *reinterpret_cast<const float4*>(w1g + (t << 2));
      r_w1q1 = *reinterpret_cast<const float4*>(w1g + ((t + 256) << 2));
      r_wbq0 = *reinterpret_cast<const float4*>(wbg + (t << 2));
      r_wbq1 = *reinterpret_cast<const float4*>(wbg + ((t + 256) << 2));
      r_wpq  = *reinterpret_cast<const float4*>(wpg + (t << 2));
    }
    const int o = (c << 3) + oo_c;
    const float* wcp = Wc + o * 12;
    r_wc0 = *reinterpret_cast<const float4*>(wcp);
    r_wc1 = *reinterpret_cast<const float4*>(wcp + 4);
    r_wc2 = *reinterpret_cast<const float4*>(wcp + 8);
    r_bc  = bc[o];
  };

  LOAD(0);

  for (int c = 0; c < NCH; ++c) {
    __syncthreads();                   // previous chunk fully consumed

    // ---- write staged weights into padded LDS rows ----
    {
      const int r0 = t >> 5,        cc0 = (t & 31) << 2;       // fi4 = t
      const int r1 = (t + 256) >> 5, cc1 = ((t + 256) & 31) << 2; // fi4 = t+256
      *reinterpret_cast<float4*>(&ws1[r0][cc0]) = r_w1q0;
      *reinterpret_cast<float4*>(&ws1[r1][cc1]) = r_w1q1;
      *reinterpret_cast<float4*>(&wsb[r0][cc0]) = r_wbq0;
      *reinterpret_cast<float4*>(&wsb[r1][cc1]) = r_wbq1;
      *reinterpret_cast<float4*>(&wsp[r0][cc0]) = r_wpq;
    }

    // ---- stage x chunk transposed; accumulate sum(x^2) ----
    {
      const float4 v = r_xv;
      esacc = fmaf(v.x, v.x, esacc); esacc = fmaf(v.y, v.y, esacc);
      esacc = fmaf(v.z, v.z, esacc); esacc = fmaf(v.w, v.w, esacc);
      const int r = skk << 2;
      xt[r + 0][stok] = v.x; xt[r + 1][stok] = v.y;
      xt[r + 2][stok] = v.z; xt[r + 3][stok] = v.w;
    }
    if (t < 8) {
      const int hh = t >> 2, kk = t & 3;
      const int col = TOK + hh, r = kk << 2;
      xt[r + 0][col] = r_hv.x; xt[r + 1][col] = r_hv.y;
      xt[r + 2][col] = r_hv.z; xt[r + 3][col] = r_hv.w;
    }
    __syncthreads();                   // staged data visible

    // keep this chunk's conv weights before the prefetch overwrites them
    float wcl[12];
    wcl[0] = r_wc0.x; wcl[1]  = r_wc0.y; wcl[2]  = r_wc0.z; wcl[3]  = r_wc0.w;
    wcl[4] = r_wc1.x; wcl[5]  = r_wc1.y; wcl[6]  = r_wc1.z; wcl[7]  = r_wc1.w;
    wcl[8] = r_wc2.x; wcl[9]  = r_wc2.y; wcl[10] = r_wc2.z; wcl[11] = r_wc2.w;
    const float bcv = r_bc;

    if (c + 1 < NCH) LOAD(c + 1);      // issue next chunk's global loads

    // ---- conv: out-ch (c*8+oo_c), tokens m2 and m2+1 ----
    {
      float pa = bcv, pb = bcv;
      const int tm1 = (m2 == 0) ? TOK : m2 - 1;
      const int tp2 = (m2 + 2 == TOK) ? TOK + 1 : m2 + 2;
#pragma unroll
      for (int i = 0; i < 4; ++i) {
        const float* row = &xt[cb_c + i][0];
        const float  xm1 = row[tm1];
        const float2 x01 = *reinterpret_cast<const float2*>(&row[m2]);
        const float  xp2 = row[tp2];
        pa = fmaf(xm1,   wcl[i * 3 + 0], pa);
        pa = fmaf(x01.x, wcl[i * 3 + 1], pa);
        pa = fmaf(x01.y, wcl[i * 3 + 2], pa);
        pb = fmaf(x01.x, wcl[i * 3 + 0], pb);
        pb = fmaf(x01.y, wcl[i * 3 + 1], pb);
        pb = fmaf(xp2,   wcl[i * 3 + 2], pb);
      }
      *reinterpret_cast<float2*>(&pf[oo_c][m2]) = make_float2(pa, pb);
    }

    // ---- x-GEMM: krow = 2*kk + kh (lane-split k-parity) ----
#pragma unroll 4
    for (int kk = 0; kk < 8; ++kk) {
      const int krow = (kk << 1) | kh;
      const float4 xa  = *reinterpret_cast<const float4*>(&xt[krow][tok0]);
      const float4 xc  = *reinterpret_cast<const float4*>(&xt[krow][tok0 + 4]);
      const float4 w1a = *reinterpret_cast<const float4*>(&ws1[krow][j0]);
      const float4 w1b = *reinterpret_cast<const float4*>(&ws1[krow][j0 + 4]);
      const float4 wba = *reinterpret_cast<const float4*>(&wsb[krow][j0]);
      const float4 wbb = *reinterpret_cast<const float4*>(&wsb[krow][j0 + 4]);
      const float xs8[8] = {xa.x, xa.y, xa.z, xa.w, xc.x, xc.y, xc.z, xc.w};
#pragma unroll
      for (int i = 0; i < 8; ++i) {
        const float xs = xs8[i];
        a1[i][0] = fmaf(xs, w1a.x, a1[i][0]);
        a1[i][1] = fmaf(xs, w1a.y, a1[i][1]);
        a1[i][2] = fmaf(xs, w1a.z, a1[i][2]);
        a1[i][3] = fmaf(xs, w1a.w, a1[i][3]);
        a1[i][4] = fmaf(xs, w1b.x, a1[i][4]);
        a1[i][5] = fmaf(xs, w1b.y, a1[i][5]);
        a1[i][6] = fmaf(xs, w1b.z, a1[i][6]);
        a1[i][7] = fmaf(xs, w1b.w, a1[i][7]);
        a2[i][0] = fmaf(xs, wba.x, a2[i][0]);
        a2[i][1] = fmaf(xs, wba.y, a2[i][1]);
        a2[i][2] = fmaf(xs, wba.z, a2[i][2]);
        a2[i][3] = fmaf(xs, wba.w, a2[i][3]);
        a2[i][4] = fmaf(xs, wbb.x, a2[i][4]);
        a2[i][5] = fmaf(xs, wbb.y, a2[i][5]);
        a2[i][6] = fmaf(xs, wbb.z, a2[i][6]);
        a2[i][7] = fmaf(xs, wbb.w, a2[i][7]);
      }
    }
    __syncthreads();                   // pf writes visible

    // ---- pf-GEMM: oo = 2*oh + kh (lane-split oo-parity) ----
#pragma unroll
    for (int oh = 0; oh < 4; ++oh) {
      const int oo = (oh << 1) | kh;
      const float4 pa4 = *reinterpret_cast<const float4*>(&pf[oo][tok0]);
      const float4 pb4 = *reinterpret_cast<const float4*>(&pf[oo][tok0 + 4]);
      const float4 wpa = *reinterpret_cast<const float4*>(&wsp[oo][j0]);
      const float4 wpb = *reinterpret_cast<const float4*>(&wsp[oo][j0 + 4]);
      const float ps8[8] = {pa4.x, pa4.y, pa4.z, pa4.w,
                            pb4.x, pb4.y, pb4.z, pb4.w};
#pragma unroll
      for (int i = 0; i < 8; ++i) {
        const float ps = ps8[i];
        a2[i][0] = fmaf(ps, wpa.x, a2[i][0]);
        a2[i][1] = fmaf(ps, wpa.y, a2[i][1]);
        a2[i][2] = fmaf(ps, wpa.z, a2[i][2]);
        a2[i][3] = fmaf(ps, wpa.w, a2[i][3]);
        a2[i][4] = fmaf(ps, wpb.x, a2[i][4]);
        a2[i][5] = fmaf(ps, wpb.y, a2[i][5]);
        a2[i][6] = fmaf(ps, wpb.z, a2[i][6]);
        a2[i][7] = fmaf(ps, wpb.w, a2[i][7]);
      }
    }
  }

  // ---- epilogue: kh-merge (shfl 32), relu+project, c8-reduce, jh via LDS ----
  {
    const float bias2 = b2[0], biasb2 = bb2[0];
    float p1v[8], p2v[8];
#pragma unroll
    for (int i = 0; i < 8; ++i) {
      float s1 = 0.f, s2 = 0.f;
#pragma unroll
      for (int jj = 0; jj < 8; ++jj) {
        const float a1f = a1[i][jj] + __shfl_xor(a1[i][jj], 32, 64);
        const float a2f = a2[i][jj] + __shfl_xor(a2[i][jj], 32, 64);
        const float h1 = a1f + b1[j0 + jj];
        if (h1 > 0.f) s1 = fmaf(h1, W2[j0 + jj], s1);
        const float h2 = a2f + bb1[j0 + jj];
        if (h2 > 0.f) s2 = fmaf(h2, Wb2[j0 + jj], s2);
      }
#pragma unroll
      for (int off = 1; off < 8; off <<= 1) {
        s1 += __shfl_xor(s1, off, 64);
        s2 += __shfl_xor(s2, off, 64);
      }
      p1v[i] = s1; p2v[i] = s2;
    }
    __syncthreads();
    if (kh == 0 && c8 == 0) {
#pragma unroll
      for (int i = 0; i < 8; ++i) {
        red1[jh][tok0 + i] = p1v[i];
        red2[jh][tok0 + i] = p2v[i];
      }
    }
    __syncthreads();
    if (t < TOK) {
      const float q1 = red1[0][t] + red1[1][t];
      const float q2 = red2[0][t] + red2[1][t];
      const int gi = b * L_ + l0 + t;
      const float content = 1.f / (1.f + expf(-(q1 + bias2)));
      const float bscore  = 1.f / (1.f + expf(-(q2 + biasb2)));
      signal[gi] = content * (1.f - bscore) * mask[gi];
    }
  }

  // ---- e epilogue: reduce over the 4 skk lanes of each token ----
  {
    float es = esacc;
    es += __shfl_xor(es, 1, 64);
    es += __shfl_xor(es, 2, 64);
    if (skk == 0) {
      const int gi = b * L_ + l0 + stok;
      const float m = mask[gi];
      e[gi] = m * m * es;
    }
  }
}

// ---------------------------------------------------------------------------
// Fused quantile + enforce. One block (1024 thr) per batch row.
// ---------------------------------------------------------------------------
__device__ __forceinline__ int chain_sim(unsigned long long w, int from) {
  int last = -1;
  while (from < 64) {
    const unsigned long long m = w & (~0ull << from);
    if (m == 0ull) break;
    const int p = __ffsll(m) - 1;
    last = p;
    from = p + 4;
  }
  return last;
}

__global__ __launch_bounds__(1024) void k_select(
    const float* __restrict__ signal,
    int* __restrict__ starts, int* __restrict__ nlast, float* __restrict__ bounds)
{
  __shared__ unsigned int bins[4][256];
  __shared__ unsigned int sel_prefix;
  __shared__ int sel_rank;
  __shared__ float sh_thr;
  __shared__ unsigned int wmin[16];
  __shared__ int wcnt[16];
  __shared__ unsigned long long cw[128];
  __shared__ unsigned char nb[L_];
  __shared__ signed char tbl[128][4];
  __shared__ int st_in[128];
  __shared__ int tsum[256];
  __shared__ int offs[257];

  const int b = blockIdx.x, t = threadIdx.x;
  const int wv = t >> 6, lane = t & 63;
  const float* s = signal + b * L_;

  float val[8];
  unsigned int key[8];
#pragma unroll
  for (int i = 0; i < 8; ++i) {
    val[i] = s[(i << 10) + t];
    const unsigned int u = __float_as_uint(val[i]);
    key[i] = (u & 0x80000000u) ? ~u : (u | 0x80000000u);
  }

  // ---- radix select rank 5733 = floor(0.7*(L-1)) ----
  if (t == 0) { sel_prefix = 0u; sel_rank = 5733; }
  __syncthreads();
  for (int round = 0; round < 4; ++round) {
    reinterpret_cast<unsigned int*>(bins)[t] = 0u;
    __syncthreads();
    const unsigned int pre = sel_prefix;
    const int shift = 24 - 8 * round;
#pragma unroll
    for (int i = 0; i < 8; ++i) {
      if (round == 0 || (key[i] >> (shift + 8)) == pre)
        atomicAdd(&bins[t >> 8][(key[i] >> shift) & 255u], 1u);
    }
    __syncthreads();
    if (t < 256)
      bins[0][t] = bins[0][t] + bins[1][t] + bins[2][t] + bins[3][t];
    __syncthreads();
    if (t < 64) {
      const unsigned int c0 = bins[0][(t << 2) + 0], c1 = bins[0][(t << 2) + 1];
      const unsigned int c2 = bins[0][(t << 2) + 2], c3 = bins[0][(t << 2) + 3];
      const unsigned int lsum = c0 + c1 + c2 + c3;
      unsigned int run = lsum;
#pragma unroll
      for (int off = 1; off < 64; off <<= 1) {
        const unsigned int v = __shfl_up(run, off, 64);
        if (t >= off) run += v;
      }
      const int r = sel_rank;
      if (r >= (int)(run - lsum) && r < (int)run) {
        int rr = r - (int)(run - lsum);
        unsigned int cbin;
        if (rr < (int)c0) { cbin = 0; }
        else if (rr < (int)(c0 + c1)) { cbin = 1; rr -= (int)c0; }
        else if (rr < (int)(c0 + c1 + c2)) { cbin = 2; rr -= (int)(c0 + c1); }
        else { cbin = 3; rr -= (int)(c0 + c1 + c2); }
        sel_rank = rr;
        sel_prefix = (pre << 8) | ((unsigned int)(t << 2) | cbin);
      }
    }
    __syncthreads();
  }
  const unsigned int k0 = sel_prefix;

  // ---- successor: count <=k0 and min of keys > k0 (tie-safe) ----
  {
    int cle = 0;
    unsigned int mgt = 0xFFFFFFFFu;
#pragma unroll
    for (int i = 0; i < 8; ++i) {
      if (key[i] <= k0) ++cle;
      else mgt = min(mgt, key[i]);
    }
#pragma unroll
    for (int off = 1; off < 64; off <<= 1) {
      cle += __shfl_xor(cle, off, 64);
      mgt = min(mgt, (unsigned int)__shfl_xor((int)mgt, off, 64));
    }
    if (lane == 0) { wcnt[wv] = cle; wmin[wv] = mgt; }
    __syncthreads();
    if (t == 0) {
      int C = 0; unsigned int M = 0xFFFFFFFFu;
      for (int g = 0; g < 16; ++g) { C += wcnt[g]; M = min(M, wmin[g]); }
      const unsigned int k1 = (C >= 5735) ? k0 : M;
      const unsigned int u0 = (k0 & 0x80000000u) ? (k0 & 0x7fffffffu) : ~k0;
      const unsigned int u1 = (k1 & 0x80000000u) ? (k1 & 0x7fffffffu) : ~k1;
      const float v0 = __uint_as_float(u0);
      const float v1 = __uint_as_float(u1);
      const float g = 0.7f * 8191.0f - 5733.0f;
      sh_thr = v0 + g * (v1 - v0);
    }
    __syncthreads();
  }
  const float thr = sh_thr;

  // ---- candidate bitmap from register values ----
#pragma unroll
  for (int i = 0; i < 8; ++i) {
    const unsigned long long m = __ballot(val[i] < thr);
    if (lane == 0) cw[(i << 4) + wv] = m;
  }
  {
    const int base = t << 3;
#pragma unroll
    for (int i = 0; i < 8; ++i) nb[base + i] = 0;
  }
  __syncthreads();
  if (t == 0) cw[127] |= (1ull << 63);   // forced candidate at L-1
  __syncthreads();

  // ---- (1) per-64-block transition tables ----
  if (t < 512) {
    const int blk = t >> 2, cls = t & 3;
    tbl[blk][cls] = (signed char)chain_sim(cw[blk], cls);
  }
  __syncthreads();

  // ---- (2) serial 128-step state scan ----
  if (t == 0) {
    int st = 0;
    for (int blk = 0; blk < 128; ++blk) {
      const int bs = blk << 6;
      st_in[blk] = st;
      int pl;
      if (blk == 0) {
        pl = chain_sim(cw[0], 4);
      } else {
        int off = st + 4 - bs;
        if (off < 0) off = 0;
        pl = tbl[blk][off];
      }
      if (pl >= 0) st = bs + pl;
    }
  }
  __syncthreads();

  // ---- (3) parallel emission of acceptance + split bytes ----
  if (t < 128) {
    const int bs = t << 6;
    const unsigned long long w = cw[t];
    int st = st_in[t];
    int from = st + 4 - bs;
    if (from < 0) from = 0;
    while (from < 64) {
      const unsigned long long m = w & (~0ull << from);
      if (m == 0ull) break;
      const int p_rel = __ffsll(m) - 1;
      const int p = bs + p_rel;
      nb[p] = 1;
      const int ps = p - st;
      const int k = (ps + 15) >> 4;
      if (k > 1) {
        int sz = ps / k; if (sz < 1) sz = 1;
        for (int j = 1; j < k; ++j) nb[st + j * sz] = 1;
      }
      st = p;
      from = p_rel + 4;
    }
  }
  __syncthreads();

  // ---- prefix scan -> starts / nlast / bounds ----
  if (t < 256) {
    const int base = t << 5;
    int ls = 0;
    for (int i = 0; i < 32; ++i) ls += nb[base + i];
    tsum[t] = ls;
  }
  __syncthreads();
  if (t == 0) {
    int r = 0;
    for (int i = 0; i < 256; ++i) { offs[i] = r; r += tsum[i]; }
    offs[256] = r;
  }
  __syncthreads();
  if (t < 256) {
    const int base = t << 5;
    int run = offs[t];
    for (int i = 0; i < 32; ++i) {
      run += nb[base + i];
      if (nb[base + i]) starts[b * L_ + run] = base + i;
    }
  }
  if (t == 0) { starts[b * L_ + 0] = 0; nlast[b] = offs[256]; }
  __syncthreads();
  const int total = offs[256];
  for (int i = t; i < L_; i += 1024)
    bounds[b * L_ + i] = (i >= 1 && i <= total) ? 1.0f : 0.0f;
}

// ---------------------------------------------------------------------------
// Segment softmax-merge: 4 waves per block; per-wave body unchanged.
// ---------------------------------------------------------------------------
__global__ __launch_bounds__(256) void k_merge(const float* __restrict__ x,
    const float* __restrict__ mask, const float* __restrict__ e,
    const int* __restrict__ starts, const int* __restrict__ nlast,
    float* __restrict__ merged)
{
  const int idx = (blockIdx.x << 2) + (threadIdx.x >> 6);
  const int b   = idx >> 13;
  const int sid = idx & (L_ - 1);
  const int n = nlast[b];
  const int lane = threadIdx.x & 63;
  const int c0 = lane << 3;
  float* o = merged + (size_t)(b * L_ + sid) * D_ + c0;
  if (sid > n) {
    const float4 z = make_float4(0.f, 0.f, 0.f, 0.f);
    reinterpret_cast<float4*>(o)[0] = z;
    reinterpret_cast<float4*>(o)[1] = z;
    return;
  }
  const int t0 = starts[b * L_ + sid];
  const int t1 = (sid < n) ? starts[b * L_ + sid + 1] : L_;
  const float* eb = e + b * L_;

  float mx = -INFINITY;
  for (int p = t0; p < t1; ++p) mx = fmaxf(mx, eb[p]);
  float den = 0.f;
  for (int p = t0; p < t1; ++p) den += expf(eb[p] - mx);

  float acc[8] = {0,0,0,0,0,0,0,0};
  for (int p = t0; p < t1; ++p) {
    const float wn = expf(eb[p] - mx) / den;
    const float sc = wn * mask[b * L_ + p];
    const float* xr = x + ((size_t)(b * L_ + p)) * D_ + c0;
    const float4 u0 = reinterpret_cast<const float4*>(xr)[0];
    const float4 u1 = reinterpret_cast<const float4*>(xr)[1];
    acc[0] = fmaf(sc, u0.x, acc[0]); acc[1] = fmaf(sc, u0.y, acc[1]);
    acc[2] = fmaf(sc, u0.z, acc[2]); acc[3] = fmaf(sc, u0.w, acc[3]);
    acc[4] = fmaf(sc, u1.x, acc[4]); acc[5] = fmaf(sc, u1.y, acc[5]);
    acc[6] = fmaf(sc, u1.z, acc[6]); acc[7] = fmaf(sc, u1.w, acc[7]);
  }
  reinterpret_cast<float4*>(o)[0] = make_float4(acc[0], acc[1], acc[2], acc[3]);
  reinterpret_cast<float4*>(o)[1] = make_float4(acc[4], acc[5], acc[6], acc[7]);
}

// ---------------------------------------------------------------------------
extern "C" void kernel_launch(void* const* d_in, const int* in_sizes, int n_in,
                              void* d_out, int out_size, void* d_ws, size_t ws_size,
                              hipStream_t stream) {
  (void)in_sizes; (void)n_in; (void)out_size; (void)ws_size;
  const float* x    = (const float*)d_in[0];
  const float* mask = (const float*)d_in[1];
  const float* W1   = (const float*)d_in[2];
  const float* b1   = (const float*)d_in[3];
  const float* W2   = (const float*)d_in[4];
  const float* b2   = (const float*)d_in[5];
  const float* Wc   = (const float*)d_in[6];
  const float* bc   = (const float*)d_in[7];
  const float* Wb1  = (const float*)d_in[8];
  const float* bb1  = (const float*)d_in[9];
  const float* Wb2  = (const float*)d_in[10];
  const float* bb2  = (const float*)d_in[11];

  float* merged = (float*)d_out;
  float* bounds = (float*)d_out + (size_t)BL_ * D_;

  char* ws = (char*)d_ws;
  float* signal = (float*)(ws);
  float* e      = (float*)(ws + (size_t)BL_ * 4);
  int*   starts = (int*)  (ws + (size_t)BL_ * 8);
  int*   nlast  = (int*)  (ws + (size_t)BL_ * 12);

  k_signal<<<BL_ / TOK, 256, 0, stream>>>(x, mask, W1, b1, W2, b2, Wc, bc,
                                          Wb1, bb1, Wb2, bb2, signal, e);
  k_select<<<B_, 1024, 0, stream>>>(signal, starts, nlast, bounds);
  k_merge<<<BL_ / 4, 256, 0, stream>>>(x, mask, e, starts, nlast, merged);
}

// Round 5
// 302.987 us; speedup vs baseline: 1.6488x; 1.0841x over previous
//
#include <hip/hip_runtime.h>
#include <math.h>

#define B_  4
#define L_  8192
#define D_  512
#define BL_ (B_*L_)
#define TOK 64
#define XS  68            // 64 tok + 2 halo + 2 pad
#define KC  16
#define NCH (D_/KC)

// ---------------------------------------------------------------------------
// Signal + e — exact R1 kernel (best measured: 165 us, VGPR 84, no spills).
// TOK=64/block (512 blocks, 2/CU), T=8 tok x J=4 j per thread; weights via
// LDS (4 b128 / 64 FMA in the x-GEMM); register prefetch of next chunk.
// R4's in-wave k-split was a no-op on LDS instr count and spilled — reverted.
// ---------------------------------------------------------------------------
__global__ __launch_bounds__(256, 2) void k_signal(
    const float* __restrict__ x, const float* __restrict__ mask,
    const float* __restrict__ W1, const float* __restrict__ b1,
    const float* __restrict__ W2, const float* __restrict__ b2,
    const float* __restrict__ Wc, const float* __restrict__ bc,
    const float* __restrict__ Wb1, const float* __restrict__ bb1,
    const float* __restrict__ Wb2, const float* __restrict__ bb2,
    float* __restrict__ signal, float* __restrict__ e)
{
  __shared__ float ws1[KC][128];   // W1 chunk rows kc..kc+15
  __shared__ float wsb[KC][128];   // Wb1 x-part chunk
  __shared__ float wsp[8][128];    // Wb1 pf-part chunk (8 conv channels/chunk)
  __shared__ float xt[KC][XS];     // x transposed; col 64 = l0-1, 65 = l0+64
  __shared__ float pf[8][XS];      // conv out chunk

  const int t   = threadIdx.x;
  const int blk = blockIdx.x;          // 512 = 4 b x 128 tiles
  const int b   = blk >> 7;
  const int l0  = (blk & 127) << 6;
  const float* xb = x + (size_t)b * L_ * D_;

  const int jq = t & 31, tw = t >> 5;
  const int j0 = jq << 2, tok0 = tw << 3;

  // x-staging / e role: all 256 threads, one float4 per chunk
  const int stok = t >> 2, skk = t & 3;
  // conv role: out-ch oo_c, adjacent token pair (m2, m2+1)
  const int oo_c = t >> 5;             // 0..7
  const int m2   = (t & 31) << 1;      // 0,2,...,62
  const int cb_c = (oo_c >> 1) << 2;   // rel in-channel base {0,4,8,12}

  const int srow = t >> 5, sc4 = (t & 31) << 2;

  float a1[8][4], a2[8][4];
#pragma unroll
  for (int i = 0; i < 8; ++i)
#pragma unroll
    for (int j = 0; j < 4; ++j) { a1[i][j] = 0.f; a2[i][j] = 0.f; }
  float esacc = 0.f;

  // prefetch registers (next chunk)
  float4 r_w1a, r_w1b, r_wba, r_wbb, r_wp, r_xv, r_hv;
  float4 r_wc0, r_wc1, r_wc2;
  float  r_bc;

  auto LOAD = [&](int c) {
    const int kc = c << 4;
    r_w1a = *reinterpret_cast<const float4*>(W1  + (size_t)(kc + srow) * 128 + sc4);
    r_w1b = *reinterpret_cast<const float4*>(W1  + (size_t)(kc + 8 + srow) * 128 + sc4);
    r_wba = *reinterpret_cast<const float4*>(Wb1 + (size_t)(kc + srow) * 128 + sc4);
    r_wbb = *reinterpret_cast<const float4*>(Wb1 + (size_t)(kc + 8 + srow) * 128 + sc4);
    r_wp  = *reinterpret_cast<const float4*>(Wb1 + (size_t)(512 + (c << 3) + srow) * 128 + sc4);
    r_xv  = *reinterpret_cast<const float4*>(xb + (size_t)(l0 + stok) * D_ + kc + (skk << 2));
    if (t < 8) {
      const int hh = t >> 2, kk = t & 3;
      const int l = hh ? (l0 + TOK) : (l0 - 1);
      r_hv = make_float4(0.f, 0.f, 0.f, 0.f);
      if (l >= 0 && l < L_)
        r_hv = *reinterpret_cast<const float4*>(xb + (size_t)l * D_ + kc + (kk << 2));
    }
    const int o = (c << 3) + oo_c;
    const float* wcp = Wc + o * 12;
    r_wc0 = *reinterpret_cast<const float4*>(wcp);
    r_wc1 = *reinterpret_cast<const float4*>(wcp + 4);
    r_wc2 = *reinterpret_cast<const float4*>(wcp + 8);
    r_bc  = bc[o];
  };

  LOAD(0);

  for (int c = 0; c < NCH; ++c) {
    __syncthreads();                   // previous chunk fully consumed

    // ---- write staged registers into LDS ----
    *reinterpret_cast<float4*>(&ws1[srow][sc4])     = r_w1a;
    *reinterpret_cast<float4*>(&ws1[8 + srow][sc4]) = r_w1b;
    *reinterpret_cast<float4*>(&wsb[srow][sc4])     = r_wba;
    *reinterpret_cast<float4*>(&wsb[8 + srow][sc4]) = r_wbb;
    *reinterpret_cast<float4*>(&wsp[srow][sc4])     = r_wp;
    {
      const float4 v = r_xv;
      esacc = fmaf(v.x, v.x, esacc); esacc = fmaf(v.y, v.y, esacc);
      esacc = fmaf(v.z, v.z, esacc); esacc = fmaf(v.w, v.w, esacc);
      const int r = skk << 2;
      xt[r + 0][stok] = v.x; xt[r + 1][stok] = v.y;
      xt[r + 2][stok] = v.z; xt[r + 3][stok] = v.w;
    }
    if (t < 8) {
      const int hh = t >> 2, kk = t & 3;
      const int col = TOK + hh, r = kk << 2;
      xt[r + 0][col] = r_hv.x; xt[r + 1][col] = r_hv.y;
      xt[r + 2][col] = r_hv.z; xt[r + 3][col] = r_hv.w;
    }
    __syncthreads();                   // staged data visible

    // keep this chunk's conv weights before the prefetch overwrites them
    float wcl[12];
    wcl[0] = r_wc0.x; wcl[1]  = r_wc0.y; wcl[2]  = r_wc0.z; wcl[3]  = r_wc0.w;
    wcl[4] = r_wc1.x; wcl[5]  = r_wc1.y; wcl[6]  = r_wc1.z; wcl[7]  = r_wc1.w;
    wcl[8] = r_wc2.x; wcl[9]  = r_wc2.y; wcl[10] = r_wc2.z; wcl[11] = r_wc2.w;
    const float bcv = r_bc;

    if (c + 1 < NCH) LOAD(c + 1);      // issue next chunk's global loads

    // ---- conv: out-ch (c*8+oo_c), tokens m2 and m2+1 ----
    {
      float pa = bcv, pb = bcv;
      const int tm1 = (m2 == 0) ? TOK : m2 - 1;
      const int tp2 = (m2 + 2 == TOK) ? TOK + 1 : m2 + 2;
#pragma unroll
      for (int i = 0; i < 4; ++i) {
        const float* row = &xt[cb_c + i][0];
        const float  xm1 = row[tm1];
        const float2 x01 = *reinterpret_cast<const float2*>(&row[m2]);
        const float  xp2 = row[tp2];
        pa = fmaf(xm1,   wcl[i * 3 + 0], pa);
        pa = fmaf(x01.x, wcl[i * 3 + 1], pa);
        pa = fmaf(x01.y, wcl[i * 3 + 2], pa);
        pb = fmaf(x01.x, wcl[i * 3 + 0], pb);
        pb = fmaf(x01.y, wcl[i * 3 + 1], pb);
        pb = fmaf(xp2,   wcl[i * 3 + 2], pb);
      }
      *reinterpret_cast<float2*>(&pf[oo_c][m2]) = make_float2(pa, pb);
    }

    // ---- GEMM x-part: 4 b128 -> 64 FMA per k ----
#pragma unroll 4
    for (int k = 0; k < KC; ++k) {
      const float4 w1 = *reinterpret_cast<const float4*>(&ws1[k][j0]);
      const float4 wb = *reinterpret_cast<const float4*>(&wsb[k][j0]);
      const float4 xa = *reinterpret_cast<const float4*>(&xt[k][tok0]);
      const float4 xc = *reinterpret_cast<const float4*>(&xt[k][tok0 + 4]);
      const float xs8[8] = {xa.x, xa.y, xa.z, xa.w, xc.x, xc.y, xc.z, xc.w};
#pragma unroll
      for (int i = 0; i < 8; ++i) {
        a1[i][0] = fmaf(xs8[i], w1.x, a1[i][0]);
        a1[i][1] = fmaf(xs8[i], w1.y, a1[i][1]);
        a1[i][2] = fmaf(xs8[i], w1.z, a1[i][2]);
        a1[i][3] = fmaf(xs8[i], w1.w, a1[i][3]);
        a2[i][0] = fmaf(xs8[i], wb.x, a2[i][0]);
        a2[i][1] = fmaf(xs8[i], wb.y, a2[i][1]);
        a2[i][2] = fmaf(xs8[i], wb.z, a2[i][2]);
        a2[i][3] = fmaf(xs8[i], wb.w, a2[i][3]);
      }
    }
    __syncthreads();                   // pf writes visible

    // ---- GEMM pf-part ----
#pragma unroll 2
    for (int oo = 0; oo < 8; ++oo) {
      const float4 wp = *reinterpret_cast<const float4*>(&wsp[oo][j0]);
      const float4 pa4 = *reinterpret_cast<const float4*>(&pf[oo][tok0]);
      const float4 pb4 = *reinterpret_cast<const float4*>(&pf[oo][tok0 + 4]);
      const float ps8[8] = {pa4.x, pa4.y, pa4.z, pa4.w, pb4.x, pb4.y, pb4.z, pb4.w};
#pragma unroll
      for (int i = 0; i < 8; ++i) {
        a2[i][0] = fmaf(ps8[i], wp.x, a2[i][0]);
        a2[i][1] = fmaf(ps8[i], wp.y, a2[i][1]);
        a2[i][2] = fmaf(ps8[i], wp.z, a2[i][2]);
        a2[i][3] = fmaf(ps8[i], wp.w, a2[i][3]);
      }
    }
  }

  // ---- epilogue: relu, project, cross-jq reduce, sigmoid ----
  {
    float b1v[4], w2v[4], bbv[4], wv2[4];
#pragma unroll
    for (int jj = 0; jj < 4; ++jj) {
      b1v[jj] = b1[j0 + jj];  w2v[jj] = W2[j0 + jj];
      bbv[jj] = bb1[j0 + jj]; wv2[jj] = Wb2[j0 + jj];
    }
    const float bias2 = b2[0], biasb2 = bb2[0];
#pragma unroll
    for (int i = 0; i < 8; ++i) {
      float p1 = 0.f, p2 = 0.f;
#pragma unroll
      for (int jj = 0; jj < 4; ++jj) {
        const float h1 = a1[i][jj] + b1v[jj];
        if (h1 > 0.f) p1 = fmaf(h1, w2v[jj], p1);
        const float h2 = a2[i][jj] + bbv[jj];
        if (h2 > 0.f) p2 = fmaf(h2, wv2[jj], p2);
      }
#pragma unroll
      for (int off = 1; off < 32; off <<= 1) {
        p1 += __shfl_xor(p1, off, 64);
        p2 += __shfl_xor(p2, off, 64);
      }
      if (jq == 0) {
        const int gi = b * L_ + l0 + tok0 + i;
        const float content = 1.f / (1.f + expf(-(p1 + bias2)));
        const float bscore  = 1.f / (1.f + expf(-(p2 + biasb2)));
        signal[gi] = content * (1.f - bscore) * mask[gi];
      }
    }
  }

  // ---- e epilogue: reduce over the 4 skk lanes of each token ----
  {
    float es = esacc;
    es += __shfl_xor(es, 1, 64);
    es += __shfl_xor(es, 2, 64);
    if (skk == 0) {
      const int gi = b * L_ + l0 + stok;
      const float m = mask[gi];
      e[gi] = m * m * es;
    }
  }
}

// ---------------------------------------------------------------------------
// Fused quantile + enforce. One block (1024 thr) per batch row.
// ---------------------------------------------------------------------------
__device__ __forceinline__ int chain_sim(unsigned long long w, int from) {
  int last = -1;
  while (from < 64) {
    const unsigned long long m = w & (~0ull << from);
    if (m == 0ull) break;
    const int p = __ffsll(m) - 1;
    last = p;
    from = p + 4;
  }
  return last;
}

__global__ __launch_bounds__(1024) void k_select(
    const float* __restrict__ signal,
    int* __restrict__ starts, int* __restrict__ nlast, float* __restrict__ bounds)
{
  __shared__ unsigned int bins[4][256];
  __shared__ unsigned int sel_prefix;
  __shared__ int sel_rank;
  __shared__ float sh_thr;
  __shared__ unsigned int wmin[16];
  __shared__ int wcnt[16];
  __shared__ unsigned long long cw[128];
  __shared__ unsigned char nb[L_];
  __shared__ signed char tbl[128][4];
  __shared__ int st_in[128];
  __shared__ int tsum[256];
  __shared__ int offs[257];

  const int b = blockIdx.x, t = threadIdx.x;
  const int wv = t >> 6, lane = t & 63;
  const float* s = signal + b * L_;

  float val[8];
  unsigned int key[8];
#pragma unroll
  for (int i = 0; i < 8; ++i) {
    val[i] = s[(i << 10) + t];
    const unsigned int u = __float_as_uint(val[i]);
    key[i] = (u & 0x80000000u) ? ~u : (u | 0x80000000u);
  }

  // ---- radix select rank 5733 = floor(0.7*(L-1)) ----
  if (t == 0) { sel_prefix = 0u; sel_rank = 5733; }
  __syncthreads();
  for (int round = 0; round < 4; ++round) {
    reinterpret_cast<unsigned int*>(bins)[t] = 0u;
    __syncthreads();
    const unsigned int pre = sel_prefix;
    const int shift = 24 - 8 * round;
#pragma unroll
    for (int i = 0; i < 8; ++i) {
      if (round == 0 || (key[i] >> (shift + 8)) == pre)
        atomicAdd(&bins[t >> 8][(key[i] >> shift) & 255u], 1u);
    }
    __syncthreads();
    if (t < 256)
      bins[0][t] = bins[0][t] + bins[1][t] + bins[2][t] + bins[3][t];
    __syncthreads();
    if (t < 64) {
      const unsigned int c0 = bins[0][(t << 2) + 0], c1 = bins[0][(t << 2) + 1];
      const unsigned int c2 = bins[0][(t << 2) + 2], c3 = bins[0][(t << 2) + 3];
      const unsigned int lsum = c0 + c1 + c2 + c3;
      unsigned int run = lsum;
#pragma unroll
      for (int off = 1; off < 64; off <<= 1) {
        const unsigned int v = __shfl_up(run, off, 64);
        if (t >= off) run += v;
      }
      const int r = sel_rank;
      if (r >= (int)(run - lsum) && r < (int)run) {
        int rr = r - (int)(run - lsum);
        unsigned int cbin;
        if (rr < (int)c0) { cbin = 0; }
        else if (rr < (int)(c0 + c1)) { cbin = 1; rr -= (int)c0; }
        else if (rr < (int)(c0 + c1 + c2)) { cbin = 2; rr -= (int)(c0 + c1); }
        else { cbin = 3; rr -= (int)(c0 + c1 + c2); }
        sel_rank = rr;
        sel_prefix = (pre << 8) | ((unsigned int)(t << 2) | cbin);
      }
    }
    __syncthreads();
  }
  const unsigned int k0 = sel_prefix;

  // ---- successor: count <=k0 and min of keys > k0 (tie-safe) ----
  {
    int cle = 0;
    unsigned int mgt = 0xFFFFFFFFu;
#pragma unroll
    for (int i = 0; i < 8; ++i) {
      if (key[i] <= k0) ++cle;
      else mgt = min(mgt, key[i]);
    }
#pragma unroll
    for (int off = 1; off < 64; off <<= 1) {
      cle += __shfl_xor(cle, off, 64);
      mgt = min(mgt, (unsigned int)__shfl_xor((int)mgt, off, 64));
    }
    if (lane == 0) { wcnt[wv] = cle; wmin[wv] = mgt; }
    __syncthreads();
    if (t == 0) {
      int C = 0; unsigned int M = 0xFFFFFFFFu;
      for (int g = 0; g < 16; ++g) { C += wcnt[g]; M = min(M, wmin[g]); }
      const unsigned int k1 = (C >= 5735) ? k0 : M;
      const unsigned int u0 = (k0 & 0x80000000u) ? (k0 & 0x7fffffffu) : ~k0;
      const unsigned int u1 = (k1 & 0x80000000u) ? (k1 & 0x7fffffffu) : ~k1;
      const float v0 = __uint_as_float(u0);
      const float v1 = __uint_as_float(u1);
      const float g = 0.7f * 8191.0f - 5733.0f;
      sh_thr = v0 + g * (v1 - v0);
    }
    __syncthreads();
  }
  const float thr = sh_thr;

  // ---- candidate bitmap from register values ----
#pragma unroll
  for (int i = 0; i < 8; ++i) {
    const unsigned long long m = __ballot(val[i] < thr);
    if (lane == 0) cw[(i << 4) + wv] = m;
  }
  {
    const int base = t << 3;
#pragma unroll
    for (int i = 0; i < 8; ++i) nb[base + i] = 0;
  }
  __syncthreads();
  if (t == 0) cw[127] |= (1ull << 63);   // forced candidate at L-1
  __syncthreads();

  // ---- (1) per-64-block transition tables ----
  if (t < 512) {
    const int blk = t >> 2, cls = t & 3;
    tbl[blk][cls] = (signed char)chain_sim(cw[blk], cls);
  }
  __syncthreads();

  // ---- (2) serial 128-step state scan ----
  if (t == 0) {
    int st = 0;
    for (int blk = 0; blk < 128; ++blk) {
      const int bs = blk << 6;
      st_in[blk] = st;
      int pl;
      if (blk == 0) {
        pl = chain_sim(cw[0], 4);
      } else {
        int off = st + 4 - bs;
        if (off < 0) off = 0;
        pl = tbl[blk][off];
      }
      if (pl >= 0) st = bs + pl;
    }
  }
  __syncthreads();

  // ---- (3) parallel emission of acceptance + split bytes ----
  if (t < 128) {
    const int bs = t << 6;
    const unsigned long long w = cw[t];
    int st = st_in[t];
    int from = st + 4 - bs;
    if (from < 0) from = 0;
    while (from < 64) {
      const unsigned long long m = w & (~0ull << from);
      if (m == 0ull) break;
      const int p_rel = __ffsll(m) - 1;
      const int p = bs + p_rel;
      nb[p] = 1;
      const int ps = p - st;
      const int k = (ps + 15) >> 4;
      if (k > 1) {
        int sz = ps / k; if (sz < 1) sz = 1;
        for (int j = 1; j < k; ++j) nb[st + j * sz] = 1;
      }
      st = p;
      from = p_rel + 4;
    }
  }
  __syncthreads();

  // ---- prefix scan -> starts / nlast / bounds ----
  if (t < 256) {
    const int base = t << 5;
    int ls = 0;
    for (int i = 0; i < 32; ++i) ls += nb[base + i];
    tsum[t] = ls;
  }
  __syncthreads();
  if (t == 0) {
    int r = 0;
    for (int i = 0; i < 256; ++i) { offs[i] = r; r += tsum[i]; }
    offs[256] = r;
  }
  __syncthreads();
  if (t < 256) {
    const int base = t << 5;
    int run = offs[t];
    for (int i = 0; i < 32; ++i) {
      run += nb[base + i];
      if (nb[base + i]) starts[b * L_ + run] = base + i;
    }
  }
  if (t == 0) { starts[b * L_ + 0] = 0; nlast[b] = offs[256]; }
  __syncthreads();
  const int total = offs[256];
  for (int i = t; i < L_; i += 1024)
    bounds[b * L_ + i] = (i >= 1 && i <= total) ? 1.0f : 0.0f;
}

// ---------------------------------------------------------------------------
// Segment softmax-merge v2: 4 waves/block. Segment e-values are loaded in ONE
// coalesced vector load (lane l -> e[t0+l]); max/denominator via shfl trees;
// per-row weight via __shfl broadcast. x-row loop runs a 2-deep explicit load
// pipeline (independent addresses) instead of R0-R4's 3 serial dependent
// passes over e. Fallback serial path guards the (never-seen) len>64 case.
// ---------------------------------------------------------------------------
__global__ __launch_bounds__(256) void k_merge(const float* __restrict__ x,
    const float* __restrict__ mask, const float* __restrict__ e,
    const int* __restrict__ starts, const int* __restrict__ nlast,
    float* __restrict__ merged)
{
  const int idx = (blockIdx.x << 2) + (threadIdx.x >> 6);
  const int b   = idx >> 13;
  const int sid = idx & (L_ - 1);
  const int n = nlast[b];
  const int lane = threadIdx.x & 63;
  const int c0 = lane << 3;
  float* o = merged + (size_t)(b * L_ + sid) * D_ + c0;
  if (sid > n) {
    const float4 z = make_float4(0.f, 0.f, 0.f, 0.f);
    reinterpret_cast<float4*>(o)[0] = z;
    reinterpret_cast<float4*>(o)[1] = z;
    return;
  }
  const int t0 = starts[b * L_ + sid];
  const int t1 = (sid < n) ? starts[b * L_ + sid + 1] : L_;
  const int len = t1 - t0;
  const float* eb = e + b * L_;

  float acc[8] = {0,0,0,0,0,0,0,0};

  if (len <= 64) {
    // ---- whole segment in-wave: 1 coalesced e load + shfl reductions ----
    const float ev = (lane < len) ? eb[t0 + lane] : -INFINITY;
    float mx = ev;
#pragma unroll
    for (int off = 1; off < 64; off <<= 1)
      mx = fmaxf(mx, __shfl_xor(mx, off, 64));
    const float ex = expf(ev - mx);          // 0 for dead lanes
    float den = ex;
#pragma unroll
    for (int off = 1; off < 64; off <<= 1)
      den += __shfl_xor(den, off, 64);
    const float mk = (lane < len) ? mask[b * L_ + t0 + lane] : 0.f;
    const float scl = (ex / den) * mk;       // per-lane: weight of row t0+lane

    // ---- x-row loop with 2-deep load pipeline ----
    const float* xr = x + (size_t)(b * L_ + t0) * D_ + c0;
    float4 u0 = reinterpret_cast<const float4*>(xr)[0];
    float4 u1 = reinterpret_cast<const float4*>(xr)[1];
    for (int r = 0; r < len; ++r) {
      float4 n0, n1;
      if (r + 1 < len) {
        const float* xn = xr + (size_t)(r + 1) * D_;
        n0 = reinterpret_cast<const float4*>(xn)[0];
        n1 = reinterpret_cast<const float4*>(xn)[1];
      }
      const float sc = __shfl(scl, r, 64);
      acc[0] = fmaf(sc, u0.x, acc[0]); acc[1] = fmaf(sc, u0.y, acc[1]);
      acc[2] = fmaf(sc, u0.z, acc[2]); acc[3] = fmaf(sc, u0.w, acc[3]);
      acc[4] = fmaf(sc, u1.x, acc[4]); acc[5] = fmaf(sc, u1.y, acc[5]);
      acc[6] = fmaf(sc, u1.z, acc[6]); acc[7] = fmaf(sc, u1.w, acc[7]);
      u0 = n0; u1 = n1;
    }
  } else {
    // ---- fallback (len > 64): original serial path ----
    float mx = -INFINITY;
    for (int p = t0; p < t1; ++p) mx = fmaxf(mx, eb[p]);
    float den = 0.f;
    for (int p = t0; p < t1; ++p) den += expf(eb[p] - mx);
    for (int p = t0; p < t1; ++p) {
      const float wn = expf(eb[p] - mx) / den;
      const float sc = wn * mask[b * L_ + p];
      const float* xr = x + ((size_t)(b * L_ + p)) * D_ + c0;
      const float4 u0 = reinterpret_cast<const float4*>(xr)[0];
      const float4 u1 = reinterpret_cast<const float4*>(xr)[1];
      acc[0] = fmaf(sc, u0.x, acc[0]); acc[1] = fmaf(sc, u0.y, acc[1]);
      acc[2] = fmaf(sc, u0.z, acc[2]); acc[3] = fmaf(sc, u0.w, acc[3]);
      acc[4] = fmaf(sc, u1.x, acc[4]); acc[5] = fmaf(sc, u1.y, acc[5]);
      acc[6] = fmaf(sc, u1.z, acc[6]); acc[7] = fmaf(sc, u1.w, acc[7]);
    }
  }
  reinterpret_cast<float4*>(o)[0] = make_float4(acc[0], acc[1], acc[2], acc[3]);
  reinterpret_cast<float4*>(o)[1] = make_float4(acc[4], acc[5], acc[6], acc[7]);
}

// ---------------------------------------------------------------------------
extern "C" void kernel_launch(void* const* d_in, const int* in_sizes, int n_in,
                              void* d_out, int out_size, void* d_ws, size_t ws_size,
                              hipStream_t stream) {
  (void)in_sizes; (void)n_in; (void)out_size; (void)ws_size;
  const float* x    = (const float*)d_in[0];
  const float* mask = (const float*)d_in[1];
  const float* W1   = (const float*)d_in[2];
  const float* b1   = (const float*)d_in[3];
  const float* W2   = (const float*)d_in[4];
  const float* b2   = (const float*)d_in[5];
  const float* Wc   = (const float*)d_in[6];
  const float* bc   = (const float*)d_in[7];
  const float* Wb1  = (const float*)d_in[8];
  const float* bb1  = (const float*)d_in[9];
  const float* Wb2  = (const float*)d_in[10];
  const float* bb2  = (const float*)d_in[11];

  float* merged = (float*)d_out;
  float* bounds = (float*)d_out + (size_t)BL_ * D_;

  char* ws = (char*)d_ws;
  float* signal = (float*)(ws);
  float* e      = (float*)(ws + (size_t)BL_ * 4);
  int*   starts = (int*)  (ws + (size_t)BL_ * 8);
  int*   nlast  = (int*)  (ws + (size_t)BL_ * 12);

  k_signal<<<BL_ / TOK, 256, 0, stream>>>(x, mask, W1, b1, W2, b2, Wc, bc,
                                          Wb1, bb1, Wb2, bb2, signal, e);
  k_select<<<B_, 1024, 0, stream>>>(signal, starts, nlast, bounds);
  k_merge<<<BL_ / 4, 256, 0, stream>>>(x, mask, e, starts, nlast, merged);
}